// Round 1
// baseline (7192.651 us; speedup 1.0000x reference)
//
#include <hip/hip_runtime.h>
#include <math.h>

// ---------------- problem constants ----------------
constexpr int NN = 100000;   // note nodes
constexpr int NB = 20000;    // beat nodes
constexpr int IN_C = 64;
constexpr int HID = 128;
constexpr int OUT_C = 32;

__device__ inline void atomic_add_f32(float* p, float v) {
    unsafeAtomicAdd(p, v);   // hw global_atomic_add_f32 on gfx950
}

// ---------------- GEMM: Y = [Y +] (A*rowscale) @ W [+ bias] [relu] ----------------
// A: n x K row-major, W: K x C row-major, Y: n x C row-major.
// W staged in LDS in K-halves (KH<=64); A tile (BM x K) staged in LDS (+4 pad).
// Thread layout: cg = tid % (C/4) -> 4 output cols; rs = tid / (C/4); RT rows each.
template<int K, int C, int BM, bool ACC, bool RELU, bool BIAS, bool ROWSCALE>
__global__ __launch_bounds__(256)
void gemm_k(const float* __restrict__ A, const float* __restrict__ W,
            const float* __restrict__ bias, const float* __restrict__ cnt,
            float rmul, float* __restrict__ Y, int n)
{
    constexpr int KH  = (K > 64) ? 64 : K;
    constexpr int NKB = K / KH;
    constexpr int CG  = C / 4;
    constexpr int RS  = 256 / CG;
    constexpr int RT  = BM / RS;
    static_assert(RT >= 1 && BM % RS == 0, "bad tile config");

    __shared__ float Ws[KH * C];
    __shared__ float As[BM][K + 4];

    const int tid = threadIdx.x;
    const int cg  = tid % CG;
    const int rs  = tid / CG;

    const int ntiles = (n + BM - 1) / BM;
    for (int tile = blockIdx.x; tile < ntiles; tile += gridDim.x) {
        const int row0 = tile * BM;
        __syncthreads();  // protect As/Ws from previous tile's readers
        // stage A tile
        for (int i = tid; i < BM * (K / 4); i += 256) {
            const int r  = i / (K / 4);
            const int kc = i % (K / 4);
            const int row = row0 + r;
            float4 a = make_float4(0.f, 0.f, 0.f, 0.f);
            if (row < n) {
                a = *reinterpret_cast<const float4*>(A + (size_t)row * K + kc * 4);
                if (ROWSCALE) {
                    const float sc = 1.0f / (fmaxf(cnt[row], 1.0f) * rmul);
                    a.x *= sc; a.y *= sc; a.z *= sc; a.w *= sc;
                }
            }
            As[r][kc * 4 + 0] = a.x;
            As[r][kc * 4 + 1] = a.y;
            As[r][kc * 4 + 2] = a.z;
            As[r][kc * 4 + 3] = a.w;
        }
        float4 acc[RT];
        #pragma unroll
        for (int i = 0; i < RT; ++i) acc[i] = make_float4(0.f, 0.f, 0.f, 0.f);

        for (int kb = 0; kb < NKB; ++kb) {
            __syncthreads();
            for (int i = tid * 4; i < KH * C; i += 1024)
                *reinterpret_cast<float4*>(&Ws[i]) =
                    *reinterpret_cast<const float4*>(W + (size_t)kb * KH * C + i);
            __syncthreads();
            #pragma unroll 8
            for (int k = 0; k < KH; ++k) {
                const float4 w = *reinterpret_cast<const float4*>(&Ws[k * C + cg * 4]);
                #pragma unroll
                for (int i = 0; i < RT; ++i) {
                    const float a = As[rs * RT + i][kb * KH + k];
                    acc[i].x = fmaf(a, w.x, acc[i].x);
                    acc[i].y = fmaf(a, w.y, acc[i].y);
                    acc[i].z = fmaf(a, w.z, acc[i].z);
                    acc[i].w = fmaf(a, w.w, acc[i].w);
                }
            }
        }
        #pragma unroll
        for (int i = 0; i < RT; ++i) {
            const int row = row0 + rs * RT + i;
            if (row >= n) continue;
            float4 o = acc[i];
            if (BIAS) {
                o.x += bias[cg * 4 + 0]; o.y += bias[cg * 4 + 1];
                o.z += bias[cg * 4 + 2]; o.w += bias[cg * 4 + 3];
            }
            float* yp = Y + (size_t)row * C + cg * 4;
            if (ACC) {
                const float4 y0 = *reinterpret_cast<const float4*>(yp);
                o.x += y0.x; o.y += y0.y; o.z += y0.z; o.w += y0.w;
            }
            if (RELU) {
                o.x = fmaxf(o.x, 0.f); o.y = fmaxf(o.y, 0.f);
                o.z = fmaxf(o.z, 0.f); o.w = fmaxf(o.w, 0.f);
            }
            *reinterpret_cast<float4*>(yp) = o;
        }
    }
}

// ---------------- edge scatter-add (gather src row, atomic add to dst row) ----------------
template<int C>
__global__ __launch_bounds__(256)
void scatter_k(const float* __restrict__ X, const int* __restrict__ src,
               const int* __restrict__ dst, int E,
               float* __restrict__ agg, float* __restrict__ cnt)
{
    constexpr int TPE = C / 4;        // threads per edge
    constexpr int EPB = 256 / TPE;    // edges per block
    const int c4 = (threadIdx.x % TPE) * 4;
    const int es = threadIdx.x / TPE;
    const long long e = (long long)blockIdx.x * EPB + es;
    if (e >= E) return;
    const int s = src[e], d = dst[e];
    const float4 v = *reinterpret_cast<const float4*>(X + (size_t)s * C + c4);
    float* ap = agg + (size_t)d * C + c4;
    atomic_add_f32(ap + 0, v.x);
    atomic_add_f32(ap + 1, v.y);
    atomic_add_f32(ap + 2, v.z);
    atomic_add_f32(ap + 3, v.w);
    if (c4 == 0) atomic_add_f32(cnt + d, 1.0f);
}

// ---------------- per-row l2-normalize T then Y += scale * T/||T|| (C=128) ----------------
__global__ __launch_bounds__(256)
void l2acc_k(const float* __restrict__ T, float* __restrict__ Y, float scale, int n)
{
    const int wid  = (int)((blockIdx.x * 256 + threadIdx.x) >> 6);
    const int lane = threadIdx.x & 63;
    if (wid >= n) return;
    const float* t = T + (size_t)wid * 128;
    const float v0 = t[lane], v1 = t[lane + 64];
    float ss = v0 * v0 + v1 * v1;
    #pragma unroll
    for (int off = 32; off > 0; off >>= 1) ss += __shfl_xor(ss, off, 64);
    const float inv = scale / fmaxf(sqrtf(ss), 1e-12f);
    float* y = Y + (size_t)wid * 128;
    y[lane]      += v0 * inv;
    y[lane + 64] += v1 * inv;
}

// ---------------- in-place x = LayerNorm(relu(x)) * g + b  (C=128) ----------------
__global__ __launch_bounds__(256)
void relu_ln_k(float* __restrict__ X, const float* __restrict__ g,
               const float* __restrict__ b, int n)
{
    const int wid  = (int)((blockIdx.x * 256 + threadIdx.x) >> 6);
    const int lane = threadIdx.x & 63;
    if (wid >= n) return;
    float* x = X + (size_t)wid * 128;
    const float v0 = fmaxf(x[lane], 0.f), v1 = fmaxf(x[lane + 64], 0.f);
    float s = v0 + v1;
    #pragma unroll
    for (int off = 32; off > 0; off >>= 1) s += __shfl_xor(s, off, 64);
    const float m  = s * (1.0f / 128.0f);
    const float d0 = v0 - m, d1 = v1 - m;
    float vv = d0 * d0 + d1 * d1;
    #pragma unroll
    for (int off = 32; off > 0; off >>= 1) vv += __shfl_xor(vv, off, 64);
    const float inv = 1.0f / sqrtf(vv * (1.0f / 128.0f) + 1e-5f);
    x[lane]      = d0 * inv * g[lane]      + b[lane];
    x[lane + 64] = d1 * inv * g[lane + 64] + b[lane + 64];
}

// ---------------- merge Wr/bl across relations per (layer, dst-type) ----------------
// Wr: (2,5,128,128), bl: (2,5,128). note <- rels {0,1,3}/3, beat <- rels {2,4}/2.
__global__ void merge_k(const float* __restrict__ Wr, const float* __restrict__ bl,
                        float* __restrict__ Wm, float* __restrict__ bm)
{
    const int li = blockIdx.y >> 1, dt = blockIdx.y & 1;
    const int idx = blockIdx.x * 256 + threadIdx.x;          // 0..16383
    const float* Wb = Wr + (size_t)li * 5 * 16384;
    const float* bb = bl + (size_t)li * 5 * 128;
    float v;
    if (dt == 0)
        v = (Wb[0 * 16384 + idx] + Wb[1 * 16384 + idx] + Wb[3 * 16384 + idx]) * (1.0f / 3.0f);
    else
        v = (Wb[2 * 16384 + idx] + Wb[4 * 16384 + idx]) * 0.5f;
    Wm[(size_t)blockIdx.y * 16384 + idx] = v;
    if (blockIdx.x == 0 && threadIdx.x < 128) {
        const int c = threadIdx.x;
        const float bv = (dt == 0)
            ? (bb[0 * 128 + c] + bb[1 * 128 + c] + bb[3 * 128 + c]) * (1.0f / 3.0f)
            : (bb[2 * 128 + c] + bb[4 * 128 + c]) * 0.5f;
        bm[blockIdx.y * 128 + c] = bv;
    }
}

// ---------------- fold eval-mode BatchNorm into mlp_W2 / b2 ----------------
// h_bn = h*s + t, s = bn_g/sqrt(1+eps), t = bn_b  =>  out = h @ (diag(s)W2) + (b2 + t@W2)
__global__ void headprep_k(const float* __restrict__ W2, const float* __restrict__ b2,
                           const float* __restrict__ bng, const float* __restrict__ bnb,
                           float* __restrict__ W2p, float* __restrict__ b2p)
{
    const int idx = blockIdx.x * 256 + threadIdx.x;
    const float is = 1.0f / sqrtf(1.0f + 1e-5f);
    if (idx < 128 * 32) {
        const int k = idx >> 5;
        W2p[idx] = W2[idx] * (bng[k] * is);
    }
    if (idx < 32) {
        float s = b2[idx];
        for (int k = 0; k < 128; ++k) s += bnb[k] * W2[k * 32 + idx];
        b2p[idx] = s;
    }
}

// ---------------- orchestration ----------------
extern "C" void kernel_launch(void* const* d_in, const int* in_sizes, int n_in,
                              void* d_out, int out_size, void* d_ws, size_t ws_size,
                              hipStream_t stream)
{
    (void)n_in; (void)out_size; (void)ws_size;

    const float* x_note = (const float*)d_in[0];
    const float* x_beat = (const float*)d_in[1];
    const int*   e_on   = (const int*)d_in[2];
    const int*   e_co   = (const int*)d_in[3];
    const int*   e_nb   = (const int*)d_in[4];
    const int*   e_bn   = (const int*)d_in[5];
    const int*   e_bb   = (const int*)d_in[6];
    const float* proj_W = (const float*)d_in[7];
    const float* proj_b = (const float*)d_in[8];
    const float* l0_Wl  = (const float*)d_in[9];
    const float* l0_bl  = (const float*)d_in[10];
    const float* l0_Wr  = (const float*)d_in[11];
    const float* Wl     = (const float*)d_in[12];
    const float* bl     = (const float*)d_in[13];
    const float* Wr     = (const float*)d_in[14];
    const float* ln_g   = (const float*)d_in[15];
    const float* ln_b   = (const float*)d_in[16];
    const float* W1     = (const float*)d_in[17];
    const float* b1     = (const float*)d_in[18];
    const float* bn_g   = (const float*)d_in[19];
    const float* bn_b   = (const float*)d_in[20];
    const float* W2     = (const float*)d_in[21];
    const float* b2     = (const float*)d_in[22];

    const int E_on = in_sizes[2] / 2, E_co = in_sizes[3] / 2, E_nb = in_sizes[4] / 2,
              E_bn = in_sizes[5] / 2, E_bb = in_sizes[6] / 2;

    // ---- workspace layout (floats), ~175 MB total ----
    float* ws = (float*)d_ws;
    size_t off = 0;
    auto alloc = [&](size_t nf) { float* p = ws + off; off += (nf + 63) & ~(size_t)63; return p; };
    float* nA  = alloc((size_t)NN * 128);
    float* nB  = alloc((size_t)NN * 128);   // also used as 'tmp' (never live simultaneously)
    float* bA  = alloc((size_t)NB * 128);
    float* bB  = alloc((size_t)NB * 128);
    float* agg = alloc((size_t)NN * 128);
    float* cnt = alloc(NN);
    float* Wm  = alloc(4 * 128 * 128);
    float* bm  = alloc(4 * 128);
    float* W2p = alloc(128 * 32);
    float* b2p = alloc(64);
    float* tmp = nB;  // alias: nB is not a live ping-pong buffer during layer 0 or the head

    // ---- weight prep (recomputed every call; graph-safe) ----
    merge_k<<<dim3(64, 4), 256, 0, stream>>>(Wr, bl, Wm, bm);
    headprep_k<<<16, 256, 0, stream>>>(W2, b2, bn_g, bn_b, W2p, b2p);

    struct RelDesc { int r, s, d; const int* e; int E; };
    const RelDesc rels[5] = {
        {0, 0, 0, e_on, E_on}, {1, 0, 0, e_co, E_co}, {2, 0, 1, e_nb, E_nb},
        {3, 1, 0, e_bn, E_bn}, {4, 1, 1, e_bb, E_bb} };
    const int nsz[2] = {NN, NB};
    const float Rdiv[2] = {3.0f, 2.0f};

    // ================= layer 0 (in 64-dim, out 128-dim, per-relation l2norm) =================
    hipMemsetAsync(nA, 0, (size_t)NN * 128 * 4, stream);
    hipMemsetAsync(bA, 0, (size_t)NB * 128 * 4, stream);
    for (int ri = 0; ri < 5; ++ri) {
        const RelDesc& R = rels[ri];
        const float* xs = R.s == 0 ? x_note : x_beat;
        const float* xd = R.d == 0 ? x_note : x_beat;
        const int ns = nsz[R.s], nd = nsz[R.d];
        float* newd = R.d == 0 ? nA : bA;
        // ps = relu(xs @ proj_W[r] + proj_b[r])  -> tmp (ns x 64)
        gemm_k<64, 64, 16, false, true, true, false><<<(ns + 15) / 16, 256, 0, stream>>>(
            xs, proj_W + (size_t)R.r * 64 * 64, proj_b + R.r * 64, nullptr, 1.f, tmp, ns);
        hipMemsetAsync(agg, 0, (size_t)nd * 64 * 4, stream);
        hipMemsetAsync(cnt, 0, (size_t)nd * 4, stream);
        scatter_k<64><<<(R.E + 15) / 16, 256, 0, stream>>>(tmp, R.e, R.e + R.E, R.E, agg, cnt);
        // o = (agg/cnt) @ l0_Wl[r] + l0_bl[r]  -> tmp (nd x 128)
        gemm_k<64, 128, 32, false, false, true, true><<<(nd + 31) / 32, 256, 0, stream>>>(
            agg, l0_Wl + (size_t)R.r * 64 * 128, l0_bl + R.r * 128, cnt, 1.f, tmp, nd);
        // tmp += xd @ l0_Wr[r]
        gemm_k<64, 128, 32, true, false, false, false><<<(nd + 31) / 32, 256, 0, stream>>>(
            xd, l0_Wr + (size_t)R.r * 64 * 128, nullptr, nullptr, 1.f, tmp, nd);
        // newd += l2norm(tmp) / R_d
        l2acc_k<<<(nd + 3) / 4, 256, 0, stream>>>(tmp, newd, 1.0f / Rdiv[R.d], nd);
    }
    relu_ln_k<<<(NN + 3) / 4, 256, 0, stream>>>(nA, ln_g, ln_b, NN);
    relu_ln_k<<<(NB + 3) / 4, 256, 0, stream>>>(bA, ln_g, ln_b, NB);

    // ================= layers 1,2 (128 -> 128, merged self-term) =================
    for (int li = 0; li < 2; ++li) {     // li==0 -> layer i=1, li==1 -> layer i=2
        float* cn  = li == 0 ? nA : nB;  float* nn  = li == 0 ? nB : nA;
        float* cb  = li == 0 ? bA : bB;  float* nb_ = li == 0 ? bB : bA;
        const float* curt[2] = {cn, cb};
        float* newt[2] = {nn, nb_};
        // self term: new = cur @ Wr_merged + b_merged (fully overwrites -> no memset needed)
        gemm_k<128, 128, 32, false, false, true, false><<<(NN + 31) / 32, 256, 0, stream>>>(
            cn, Wm + (size_t)(li * 2 + 0) * 16384, bm + (li * 2 + 0) * 128, nullptr, 1.f, nn, NN);
        gemm_k<128, 128, 32, false, false, true, false><<<(NB + 31) / 32, 256, 0, stream>>>(
            cb, Wm + (size_t)(li * 2 + 1) * 16384, bm + (li * 2 + 1) * 128, nullptr, 1.f, nb_, NB);
        for (int ri = 0; ri < 5; ++ri) {
            const RelDesc& R = rels[ri];
            const int nd = nsz[R.d];
            hipMemsetAsync(agg, 0, (size_t)nd * 128 * 4, stream);
            hipMemsetAsync(cnt, 0, (size_t)nd * 4, stream);
            scatter_k<128><<<(R.E + 7) / 8, 256, 0, stream>>>(curt[R.s], R.e, R.e + R.E, R.E, agg, cnt);
            // new_d += (agg / (cnt * R_d)) @ Wl[li][r]
            gemm_k<128, 128, 32, true, false, false, true><<<(nd + 31) / 32, 256, 0, stream>>>(
                agg, Wl + (size_t)(li * 5 + R.r) * 16384, nullptr, cnt, Rdiv[R.d], newt[R.d], nd);
        }
        if (li == 0) {
            relu_ln_k<<<(NN + 3) / 4, 256, 0, stream>>>(nn,  ln_g + 128, ln_b + 128, NN);
            relu_ln_k<<<(NB + 3) / 4, 256, 0, stream>>>(nb_, ln_g + 128, ln_b + 128, NB);
        }
    }

    // ================= head: out = relu(note @ W1 + b1) @ W2p + b2p =================
    // layer 2 wrote note features into nA; tmp(=nB) is free again.
    gemm_k<128, 128, 32, false, true, true, false><<<(NN + 31) / 32, 256, 0, stream>>>(
        nA, W1, b1, nullptr, 1.f, tmp, NN);
    gemm_k<128, 32, 32, false, false, true, false><<<(NN + 31) / 32, 256, 0, stream>>>(
        tmp, W2p, b2p, nullptr, 1.f, (float*)d_out, NN);
}

// Round 2
// 1932.790 us; speedup vs baseline: 3.7214x; 3.7214x over previous
//
#include <hip/hip_runtime.h>
#include <math.h>

// ---------------- problem constants ----------------
constexpr int NN = 100000;   // note nodes
constexpr int NB = 20000;    // beat nodes
constexpr int LTOT = 3 * NN + 2 * NB;  // concatenated CSR rows: rel0(N),rel1(N),rel2(B),rel3(N),rel4(B)

// ---------------- GEMM: Y = [Y +] A @ W [+ bias] [relu] ----------------
// A: n x K row-major, W: K x C row-major, Y: n x C row-major.
template<int K, int C, int BM, bool ACC, bool RELU, bool BIAS>
__global__ __launch_bounds__(256)
void gemm_k(const float* __restrict__ A, const float* __restrict__ W,
            const float* __restrict__ bias, float* __restrict__ Y, int n)
{
    constexpr int KH  = (K > 64) ? 64 : K;
    constexpr int NKB = K / KH;
    constexpr int CG  = C / 4;
    constexpr int RS  = 256 / CG;
    constexpr int RT  = BM / RS;
    static_assert(RT >= 1 && BM % RS == 0, "bad tile config");

    __shared__ float Ws[KH * C];
    __shared__ float As[BM][K + 4];

    const int tid = threadIdx.x;
    const int cg  = tid % CG;
    const int rs  = tid / CG;

    const int ntiles = (n + BM - 1) / BM;
    for (int tile = blockIdx.x; tile < ntiles; tile += gridDim.x) {
        const int row0 = tile * BM;
        __syncthreads();  // protect As/Ws from previous tile's readers
        for (int i = tid; i < BM * (K / 4); i += 256) {
            const int r  = i / (K / 4);
            const int kc = i % (K / 4);
            const int row = row0 + r;
            float4 a = make_float4(0.f, 0.f, 0.f, 0.f);
            if (row < n)
                a = *reinterpret_cast<const float4*>(A + (size_t)row * K + kc * 4);
            As[r][kc * 4 + 0] = a.x;
            As[r][kc * 4 + 1] = a.y;
            As[r][kc * 4 + 2] = a.z;
            As[r][kc * 4 + 3] = a.w;
        }
        float4 acc[RT];
        #pragma unroll
        for (int i = 0; i < RT; ++i) acc[i] = make_float4(0.f, 0.f, 0.f, 0.f);

        for (int kb = 0; kb < NKB; ++kb) {
            __syncthreads();
            for (int i = tid * 4; i < KH * C; i += 1024)
                *reinterpret_cast<float4*>(&Ws[i]) =
                    *reinterpret_cast<const float4*>(W + (size_t)kb * KH * C + i);
            __syncthreads();
            #pragma unroll 8
            for (int k = 0; k < KH; ++k) {
                const float4 w = *reinterpret_cast<const float4*>(&Ws[k * C + cg * 4]);
                #pragma unroll
                for (int i = 0; i < RT; ++i) {
                    const float a = As[rs * RT + i][kb * KH + k];
                    acc[i].x = fmaf(a, w.x, acc[i].x);
                    acc[i].y = fmaf(a, w.y, acc[i].y);
                    acc[i].z = fmaf(a, w.z, acc[i].z);
                    acc[i].w = fmaf(a, w.w, acc[i].w);
                }
            }
        }
        #pragma unroll
        for (int i = 0; i < RT; ++i) {
            const int row = row0 + rs * RT + i;
            if (row >= n) continue;
            float4 o = acc[i];
            if (BIAS) {
                o.x += bias[cg * 4 + 0]; o.y += bias[cg * 4 + 1];
                o.z += bias[cg * 4 + 2]; o.w += bias[cg * 4 + 3];
            }
            float* yp = Y + (size_t)row * C + cg * 4;
            if (ACC) {
                const float4 y0 = *reinterpret_cast<const float4*>(yp);
                o.x += y0.x; o.y += y0.y; o.z += y0.z; o.w += y0.w;
            }
            if (RELU) {
                o.x = fmaxf(o.x, 0.f); o.y = fmaxf(o.y, 0.f);
                o.z = fmaxf(o.z, 0.f); o.w = fmaxf(o.w, 0.f);
            }
            *reinterpret_cast<float4*>(yp) = o;
        }
    }
}

// ---------------- CSR build ----------------
__global__ __launch_bounds__(256)
void hist_k(const int* __restrict__ edge, int E, int* __restrict__ deg, int rowoff)
{
    const int e = blockIdx.x * 256 + threadIdx.x;
    if (e < E) atomicAdd(&deg[rowoff + edge[e + E]], 1);
}

// block-level inclusive scan, 2048 elems/block; writes out[i+1], block sums to bsum
__global__ __launch_bounds__(256)
void scan1_k(const int* __restrict__ in, int* __restrict__ out, int* __restrict__ bsum, int n)
{
    __shared__ int wsum[4];
    const int base = blockIdx.x * 2048 + threadIdx.x * 8;
    int v[8]; int t = 0;
    #pragma unroll
    for (int k = 0; k < 8; ++k) { const int idx = base + k; v[k] = (idx < n) ? in[idx] : 0; t += v[k]; }
    int sc = t;
    #pragma unroll
    for (int off = 1; off < 64; off <<= 1) {
        const int u = __shfl_up(sc, off, 64);
        if ((threadIdx.x & 63) >= off) sc += u;
    }
    const int w = threadIdx.x >> 6, lane = threadIdx.x & 63;
    if (lane == 63) wsum[w] = sc;
    __syncthreads();
    int woff = 0;
    for (int i = 0; i < w; ++i) woff += wsum[i];
    int run = sc - t + woff;  // exclusive prefix for this thread
    #pragma unroll
    for (int k = 0; k < 8; ++k) {
        const int idx = base + k;
        run += v[k];
        if (idx < n) out[idx + 1] = run;
    }
    if (threadIdx.x == 255) bsum[blockIdx.x] = run;  // block total
}

__global__ void scan2_k(int* bsum, int nb)
{
    if (threadIdx.x == 0 && blockIdx.x == 0) {
        int acc = 0;
        for (int i = 0; i < nb; ++i) { acc += bsum[i]; bsum[i] = acc; }
    }
}

__global__ __launch_bounds__(256)
void scan3_k(int* __restrict__ rowptr, const int* __restrict__ bsum, int n)
{
    const int i = blockIdx.x * 256 + threadIdx.x;
    if (i == 0) rowptr[0] = 0;
    if (i < n) {
        const int b = i >> 11;
        if (b > 0) rowptr[i + 1] += bsum[b - 1];
    }
}

__global__ __launch_bounds__(256)
void fill_k(const int* __restrict__ edge, int E, const int* __restrict__ rowptr,
            int rowoff, int* __restrict__ next, int* __restrict__ colsrc)
{
    const int e = blockIdx.x * 256 + threadIdx.x;
    if (e >= E) return;
    const int s = edge[e], d = edge[e + E];
    const int p = atomicAdd(&next[rowoff + d], 1);
    colsrc[rowptr[rowoff + d] + p] = s;
}

// ---------------- CSR mean-aggregate: out[i] = scale * mean_{s in N(i)} X[s] ----------------
template<int C>
__global__ __launch_bounds__(256)
void aggc_k(const float* __restrict__ X, const int* __restrict__ rowptr,
            const int* __restrict__ colsrc, int rowoff, int n, float scale,
            float* __restrict__ out)
{
    const int wid  = (int)((blockIdx.x * 256 + threadIdx.x) >> 6);
    const int lane = threadIdx.x & 63;
    if (wid >= n) return;
    const int beg = rowptr[rowoff + wid], end = rowptr[rowoff + wid + 1];
    float a0 = 0.f, a1 = 0.f;
    for (int j = beg; j < end; ++j) {
        const int s = colsrc[j];
        const float* xp = X + (size_t)s * C;
        a0 += xp[lane];
        if (C == 128) a1 += xp[lane + 64];
    }
    const float m = scale / fmaxf((float)(end - beg), 1.0f);
    float* op = out + (size_t)wid * C;
    op[lane] = a0 * m;
    if (C == 128) op[lane + 64] = a1 * m;
}

// ---------------- per-row l2-normalize T then Y += scale * T/||T|| (C=128) ----------------
__global__ __launch_bounds__(256)
void l2acc_k(const float* __restrict__ T, float* __restrict__ Y, float scale, int n)
{
    const int wid  = (int)((blockIdx.x * 256 + threadIdx.x) >> 6);
    const int lane = threadIdx.x & 63;
    if (wid >= n) return;
    const float* t = T + (size_t)wid * 128;
    const float v0 = t[lane], v1 = t[lane + 64];
    float ss = v0 * v0 + v1 * v1;
    #pragma unroll
    for (int off = 32; off > 0; off >>= 1) ss += __shfl_xor(ss, off, 64);
    const float inv = scale / fmaxf(sqrtf(ss), 1e-12f);
    float* y = Y + (size_t)wid * 128;
    y[lane]      += v0 * inv;
    y[lane + 64] += v1 * inv;
}

// ---------------- in-place x = LayerNorm(relu(x)) * g + b  (C=128) ----------------
__global__ __launch_bounds__(256)
void relu_ln_k(float* __restrict__ X, const float* __restrict__ g,
               const float* __restrict__ b, int n)
{
    const int wid  = (int)((blockIdx.x * 256 + threadIdx.x) >> 6);
    const int lane = threadIdx.x & 63;
    if (wid >= n) return;
    float* x = X + (size_t)wid * 128;
    const float v0 = fmaxf(x[lane], 0.f), v1 = fmaxf(x[lane + 64], 0.f);
    float s = v0 + v1;
    #pragma unroll
    for (int off = 32; off > 0; off >>= 1) s += __shfl_xor(s, off, 64);
    const float m  = s * (1.0f / 128.0f);
    const float d0 = v0 - m, d1 = v1 - m;
    float vv = d0 * d0 + d1 * d1;
    #pragma unroll
    for (int off = 32; off > 0; off >>= 1) vv += __shfl_xor(vv, off, 64);
    const float inv = 1.0f / sqrtf(vv * (1.0f / 128.0f) + 1e-5f);
    x[lane]      = d0 * inv * g[lane]      + b[lane];
    x[lane + 64] = d1 * inv * g[lane + 64] + b[lane + 64];
}

// ---------------- merge Wr/bl across relations per (layer, dst-type) ----------------
__global__ void merge_k(const float* __restrict__ Wr, const float* __restrict__ bl,
                        float* __restrict__ Wm, float* __restrict__ bm)
{
    const int li = blockIdx.y >> 1, dt = blockIdx.y & 1;
    const int idx = blockIdx.x * 256 + threadIdx.x;          // 0..16383
    const float* Wb = Wr + (size_t)li * 5 * 16384;
    const float* bb = bl + (size_t)li * 5 * 128;
    float v;
    if (dt == 0)
        v = (Wb[0 * 16384 + idx] + Wb[1 * 16384 + idx] + Wb[3 * 16384 + idx]) * (1.0f / 3.0f);
    else
        v = (Wb[2 * 16384 + idx] + Wb[4 * 16384 + idx]) * 0.5f;
    Wm[(size_t)blockIdx.y * 16384 + idx] = v;
    if (blockIdx.x == 0 && threadIdx.x < 128) {
        const int c = threadIdx.x;
        const float bv = (dt == 0)
            ? (bb[0 * 128 + c] + bb[1 * 128 + c] + bb[3 * 128 + c]) * (1.0f / 3.0f)
            : (bb[2 * 128 + c] + bb[4 * 128 + c]) * 0.5f;
        bm[blockIdx.y * 128 + c] = bv;
    }
}

// ---------------- fold eval-mode BatchNorm into mlp_W2 / b2 ----------------
__global__ void headprep_k(const float* __restrict__ W2, const float* __restrict__ b2,
                           const float* __restrict__ bng, const float* __restrict__ bnb,
                           float* __restrict__ W2p, float* __restrict__ b2p)
{
    const int idx = blockIdx.x * 256 + threadIdx.x;
    const float is = 1.0f / sqrtf(1.0f + 1e-5f);
    if (idx < 128 * 32) {
        const int k = idx >> 5;
        W2p[idx] = W2[idx] * (bng[k] * is);
    }
    if (idx < 32) {
        float s = b2[idx];
        for (int k = 0; k < 128; ++k) s += bnb[k] * W2[k * 32 + idx];
        b2p[idx] = s;
    }
}

// ---------------- orchestration ----------------
extern "C" void kernel_launch(void* const* d_in, const int* in_sizes, int n_in,
                              void* d_out, int out_size, void* d_ws, size_t ws_size,
                              hipStream_t stream)
{
    (void)n_in; (void)out_size; (void)ws_size;

    const float* x_note = (const float*)d_in[0];
    const float* x_beat = (const float*)d_in[1];
    const int*   e_on   = (const int*)d_in[2];
    const int*   e_co   = (const int*)d_in[3];
    const int*   e_nb   = (const int*)d_in[4];
    const int*   e_bn   = (const int*)d_in[5];
    const int*   e_bb   = (const int*)d_in[6];
    const float* proj_W = (const float*)d_in[7];
    const float* proj_b = (const float*)d_in[8];
    const float* l0_Wl  = (const float*)d_in[9];
    const float* l0_bl  = (const float*)d_in[10];
    const float* l0_Wr  = (const float*)d_in[11];
    const float* Wl     = (const float*)d_in[12];
    const float* bl     = (const float*)d_in[13];
    const float* Wr     = (const float*)d_in[14];
    const float* ln_g   = (const float*)d_in[15];
    const float* ln_b   = (const float*)d_in[16];
    const float* W1     = (const float*)d_in[17];
    const float* b1     = (const float*)d_in[18];
    const float* bn_g   = (const float*)d_in[19];
    const float* bn_b   = (const float*)d_in[20];
    const float* W2     = (const float*)d_in[21];
    const float* b2     = (const float*)d_in[22];

    const int E_on = in_sizes[2] / 2, E_co = in_sizes[3] / 2, E_nb = in_sizes[4] / 2,
              E_bn = in_sizes[5] / 2, E_bb = in_sizes[6] / 2;
    const int ETOT = E_on + E_co + E_nb + E_bn + E_bb;

    // ---- workspace layout ----
    float* ws = (float*)d_ws;
    size_t off = 0;
    auto alloc = [&](size_t nf) { float* p = ws + off; off += (nf + 63) & ~(size_t)63; return p; };
    float* nA   = alloc((size_t)NN * 128);
    float* nB   = alloc((size_t)NN * 128);   // also 'tmp' (never live simultaneously)
    float* bA   = alloc((size_t)NB * 128);
    float* bB   = alloc((size_t)NB * 128);
    float* agg  = alloc((size_t)NN * 128);
    float* Wm   = alloc(4 * 128 * 128);
    float* bm   = alloc(4 * 128);
    float* W2p  = alloc(128 * 32);
    float* b2p  = alloc(64);
    int* rowptr = (int*)alloc(LTOT + 64);    // LTOT+1 ints
    int* deg    = (int*)alloc(LTOT);         // reused as 'next' for fill
    int* colsrc = (int*)alloc(ETOT);
    int* bsum   = (int*)alloc(256);
    float* tmp  = nB;

    struct RelDesc { int r, s, d; const int* e; int E; int rowoff; };
    const RelDesc rels[5] = {
        {0, 0, 0, e_on, E_on, 0},
        {1, 0, 0, e_co, E_co, NN},
        {2, 0, 1, e_nb, E_nb, 2 * NN},
        {3, 1, 0, e_bn, E_bn, 2 * NN + NB},
        {4, 1, 1, e_bb, E_bb, 3 * NN + NB} };
    const int nsz[2] = {NN, NB};
    const float Rdiv[2] = {3.0f, 2.0f};

    // ---- build concatenated CSR (once per call; reused by all 3 layers) ----
    hipMemsetAsync(deg, 0, (size_t)LTOT * 4, stream);
    for (int ri = 0; ri < 5; ++ri)
        hist_k<<<(rels[ri].E + 255) / 256, 256, 0, stream>>>(rels[ri].e, rels[ri].E, deg, rels[ri].rowoff);
    const int NBLK = (LTOT + 2047) / 2048;
    scan1_k<<<NBLK, 256, 0, stream>>>(deg, rowptr, bsum, LTOT);
    scan2_k<<<1, 64, 0, stream>>>(bsum, NBLK);
    scan3_k<<<(LTOT + 255) / 256, 256, 0, stream>>>(rowptr, bsum, LTOT);
    hipMemsetAsync(deg, 0, (size_t)LTOT * 4, stream);  // reuse as fill cursor
    for (int ri = 0; ri < 5; ++ri)
        fill_k<<<(rels[ri].E + 255) / 256, 256, 0, stream>>>(rels[ri].e, rels[ri].E, rowptr,
                                                             rels[ri].rowoff, deg, colsrc);

    // ---- weight prep ----
    merge_k<<<dim3(64, 4), 256, 0, stream>>>(Wr, bl, Wm, bm);
    headprep_k<<<16, 256, 0, stream>>>(W2, b2, bn_g, bn_b, W2p, b2p);

    // ================= layer 0 (64 -> 128, per-relation l2norm) =================
    hipMemsetAsync(nA, 0, (size_t)NN * 128 * 4, stream);
    hipMemsetAsync(bA, 0, (size_t)NB * 128 * 4, stream);
    for (int ri = 0; ri < 5; ++ri) {
        const RelDesc& R = rels[ri];
        const float* xs = R.s == 0 ? x_note : x_beat;
        const float* xd = R.d == 0 ? x_note : x_beat;
        const int ns = nsz[R.s], nd = nsz[R.d];
        float* newd = R.d == 0 ? nA : bA;
        // ps = relu(xs @ proj_W[r] + proj_b[r])  -> tmp (ns x 64)
        gemm_k<64, 64, 16, false, true, true><<<(ns + 15) / 16, 256, 0, stream>>>(
            xs, proj_W + (size_t)R.r * 64 * 64, proj_b + R.r * 64, tmp, ns);
        // agg = mean_{src} ps  (mean folded into aggregator)
        aggc_k<64><<<(nd + 3) / 4, 256, 0, stream>>>(tmp, rowptr, colsrc, R.rowoff, nd, 1.0f, agg);
        // o = agg @ l0_Wl[r] + l0_bl[r]  -> tmp (nd x 128)
        gemm_k<64, 128, 32, false, false, true><<<(nd + 31) / 32, 256, 0, stream>>>(
            agg, l0_Wl + (size_t)R.r * 64 * 128, l0_bl + R.r * 128, tmp, nd);
        // tmp += xd @ l0_Wr[r]
        gemm_k<64, 128, 32, true, false, false><<<(nd + 31) / 32, 256, 0, stream>>>(
            xd, l0_Wr + (size_t)R.r * 64 * 128, nullptr, tmp, nd);
        // newd += l2norm(tmp) / R_d
        l2acc_k<<<(nd + 3) / 4, 256, 0, stream>>>(tmp, newd, 1.0f / Rdiv[R.d], nd);
    }
    relu_ln_k<<<(NN + 3) / 4, 256, 0, stream>>>(nA, ln_g, ln_b, NN);
    relu_ln_k<<<(NB + 3) / 4, 256, 0, stream>>>(bA, ln_g, ln_b, NB);

    // ================= layers 1,2 (128 -> 128, merged self-term) =================
    for (int li = 0; li < 2; ++li) {
        float* cn  = li == 0 ? nA : nB;  float* nn  = li == 0 ? nB : nA;
        float* cb  = li == 0 ? bA : bB;  float* nb_ = li == 0 ? bB : bA;
        const float* curt[2] = {cn, cb};
        float* newt[2] = {nn, nb_};
        // self term: new = cur @ Wr_merged + b_merged
        gemm_k<128, 128, 32, false, false, true><<<(NN + 31) / 32, 256, 0, stream>>>(
            cn, Wm + (size_t)(li * 2 + 0) * 16384, bm + (li * 2 + 0) * 128, nn, NN);
        gemm_k<128, 128, 32, false, false, true><<<(NB + 31) / 32, 256, 0, stream>>>(
            cb, Wm + (size_t)(li * 2 + 1) * 16384, bm + (li * 2 + 1) * 128, nb_, NB);
        for (int ri = 0; ri < 5; ++ri) {
            const RelDesc& R = rels[ri];
            const int nd = nsz[R.d];
            // agg = mean_{src} cur_s / R_d   (both divisors folded into aggregator)
            aggc_k<128><<<(nd + 3) / 4, 256, 0, stream>>>(
                curt[R.s], rowptr, colsrc, R.rowoff, nd, 1.0f / Rdiv[R.d], agg);
            // new_d += agg @ Wl[li][r]
            gemm_k<128, 128, 32, true, false, false><<<(nd + 31) / 32, 256, 0, stream>>>(
                agg, Wl + (size_t)(li * 5 + R.r) * 16384, nullptr, newt[R.d], nd);
        }
        if (li == 0) {
            relu_ln_k<<<(NN + 3) / 4, 256, 0, stream>>>(nn,  ln_g + 128, ln_b + 128, NN);
            relu_ln_k<<<(NB + 3) / 4, 256, 0, stream>>>(nb_, ln_g + 128, ln_b + 128, NB);
        }
    }

    // ================= head: out = relu(note @ W1 + b1) @ W2p + b2p =================
    gemm_k<128, 128, 32, false, true, true><<<(NN + 31) / 32, 256, 0, stream>>>(
        nA, W1, b1, tmp, NN);
    gemm_k<128, 32, 32, false, false, true><<<(NN + 31) / 32, 256, 0, stream>>>(
        tmp, W2p, b2p, (float*)d_out, NN);
}

// Round 3
// 1906.289 us; speedup vs baseline: 3.7731x; 1.0139x over previous
//
#include <hip/hip_runtime.h>
#include <math.h>

// ---------------- problem constants ----------------
constexpr int NN = 100000;   // note nodes
constexpr int NB = 20000;    // beat nodes
constexpr int LTOT = 3 * NN + 2 * NB;  // concatenated CSR rows

// ---------------- GEMM: Y = [Y +] [A1|A2] @ [W1;W2] [+ bias] [relu] ----------------
// A1: n x K1, A2: n x K2 (row-major), W1: K1 x C, W2: K2 x C, Y: n x C.
// A tile stored TRANSPOSED in LDS: As[k][r], XOR-swizzled col' = r ^ ((k&7)<<2)
// -> conflict-free staging writes AND b128 fragment reads, 16B alignment kept.
// Micro-tile: RT rows x 4 cols per thread, both operands read as wide ds_read.
template<int K1, int K2, int C, int BM, bool ACC, bool RELU, bool BIAS>
__global__ __launch_bounds__(256)
void gemm_k(const float* __restrict__ A1, const float* __restrict__ A2,
            const float* __restrict__ W1, const float* __restrict__ W2,
            const float* __restrict__ bias, float* __restrict__ Y, int n)
{
    constexpr int K   = K1 + K2;
    constexpr int KH  = (K > 64) ? 64 : K;
    constexpr int NKB = K / KH;
    constexpr int CG  = C / 4;        // column groups (4 cols each)
    constexpr int RS  = 256 / CG;     // row groups
    constexpr int RT  = BM / RS;      // rows per thread
    constexpr int K4  = K / 4;
    static_assert(BM % RS == 0 && (RT == 1 || RT == 2 || RT == 4), "bad tile");

    __shared__ float Ws[KH * C];      // [k][c], swizzled c' = c ^ ((k&7)<<2)
    __shared__ float As[K * BM];      // [k][r], swizzled r' = r ^ ((k&7)<<2)

    const int tid = threadIdx.x;
    const int cg  = tid % CG;
    const int rs  = tid / CG;

    const int ntiles = (n + BM - 1) / BM;
    for (int tile = blockIdx.x; tile < ntiles; tile += gridDim.x) {
        const int row0 = tile * BM;
        __syncthreads();  // protect As/Ws from previous tile's readers
        // ---- stage A tile (transposed + swizzled) ----
        for (int i = tid; i < BM * K4; i += 256) {
            const int r   = i / K4;
            const int kc4 = i % K4;
            const int kc  = kc4 * 4;
            const int row = row0 + r;
            float4 a = make_float4(0.f, 0.f, 0.f, 0.f);
            if (row < n) {
                a = (K2 == 0 || kc < K1)
                  ? *reinterpret_cast<const float4*>(A1 + (size_t)row * K1 + kc)
                  : *reinterpret_cast<const float4*>(A2 + (size_t)row * K2 + (kc - K1));
            }
            As[(kc + 0) * BM + (r ^ (((kc + 0) & 7) << 2))] = a.x;
            As[(kc + 1) * BM + (r ^ (((kc + 1) & 7) << 2))] = a.y;
            As[(kc + 2) * BM + (r ^ (((kc + 2) & 7) << 2))] = a.z;
            As[(kc + 3) * BM + (r ^ (((kc + 3) & 7) << 2))] = a.w;
        }

        float4 acc[RT];
        #pragma unroll
        for (int i = 0; i < RT; ++i) acc[i] = make_float4(0.f, 0.f, 0.f, 0.f);

        for (int kb = 0; kb < NKB; ++kb) {
            __syncthreads();
            // ---- stage W chunk (swizzled) ----
            for (int i = tid * 4; i < KH * C; i += 1024) {
                const int kk = i / C, c = i % C;
                const int kg = kb * KH + kk;     // global k
                const float4 wv = (K2 == 0 || kg < K1)
                  ? *reinterpret_cast<const float4*>(W1 + (size_t)kg * C + c)
                  : *reinterpret_cast<const float4*>(W2 + (size_t)(kg - K1) * C + c);
                *reinterpret_cast<float4*>(&Ws[kk * C + (c ^ ((kk & 7) << 2))]) = wv;
            }
            __syncthreads();
            #pragma unroll 8
            for (int kk = 0; kk < KH; ++kk) {
                const int sw = (kk & 7) << 2;
                const int kg = kb * KH + kk;
                const float4 w = *reinterpret_cast<const float4*>(&Ws[kk * C + ((cg * 4) ^ sw)]);
                if (RT == 4) {
                    const float4 a = *reinterpret_cast<const float4*>(&As[kg * BM + ((rs * 4) ^ sw)]);
                    acc[0].x = fmaf(a.x, w.x, acc[0].x); acc[0].y = fmaf(a.x, w.y, acc[0].y);
                    acc[0].z = fmaf(a.x, w.z, acc[0].z); acc[0].w = fmaf(a.x, w.w, acc[0].w);
                    acc[1].x = fmaf(a.y, w.x, acc[1].x); acc[1].y = fmaf(a.y, w.y, acc[1].y);
                    acc[1].z = fmaf(a.y, w.z, acc[1].z); acc[1].w = fmaf(a.y, w.w, acc[1].w);
                    acc[2].x = fmaf(a.z, w.x, acc[2].x); acc[2].y = fmaf(a.z, w.y, acc[2].y);
                    acc[2].z = fmaf(a.z, w.z, acc[2].z); acc[2].w = fmaf(a.z, w.w, acc[2].w);
                    acc[3].x = fmaf(a.w, w.x, acc[3].x); acc[3].y = fmaf(a.w, w.y, acc[3].y);
                    acc[3].z = fmaf(a.w, w.z, acc[3].z); acc[3].w = fmaf(a.w, w.w, acc[3].w);
                } else if (RT == 2) {
                    const float2 a = *reinterpret_cast<const float2*>(&As[kg * BM + ((rs * 2) ^ sw)]);
                    acc[0].x = fmaf(a.x, w.x, acc[0].x); acc[0].y = fmaf(a.x, w.y, acc[0].y);
                    acc[0].z = fmaf(a.x, w.z, acc[0].z); acc[0].w = fmaf(a.x, w.w, acc[0].w);
                    acc[1].x = fmaf(a.y, w.x, acc[1].x); acc[1].y = fmaf(a.y, w.y, acc[1].y);
                    acc[1].z = fmaf(a.y, w.z, acc[1].z); acc[1].w = fmaf(a.y, w.w, acc[1].w);
                } else {
                    const float a = As[kg * BM + (rs ^ sw)];
                    acc[0].x = fmaf(a, w.x, acc[0].x); acc[0].y = fmaf(a, w.y, acc[0].y);
                    acc[0].z = fmaf(a, w.z, acc[0].z); acc[0].w = fmaf(a, w.w, acc[0].w);
                }
            }
        }
        // ---- epilogue ----
        #pragma unroll
        for (int i = 0; i < RT; ++i) {
            const int row = row0 + rs * RT + i;
            if (row >= n) continue;
            float4 o = acc[i];
            if (BIAS) {
                o.x += bias[cg * 4 + 0]; o.y += bias[cg * 4 + 1];
                o.z += bias[cg * 4 + 2]; o.w += bias[cg * 4 + 3];
            }
            float* yp = Y + (size_t)row * C + cg * 4;
            if (ACC) {
                const float4 y0 = *reinterpret_cast<const float4*>(yp);
                o.x += y0.x; o.y += y0.y; o.z += y0.z; o.w += y0.w;
            }
            if (RELU) {
                o.x = fmaxf(o.x, 0.f); o.y = fmaxf(o.y, 0.f);
                o.z = fmaxf(o.z, 0.f); o.w = fmaxf(o.w, 0.f);
            }
            *reinterpret_cast<float4*>(yp) = o;
        }
    }
}

// ---------------- CSR build ----------------
__global__ __launch_bounds__(256)
void hist_k(const int* __restrict__ edge, int E, int* __restrict__ deg, int rowoff)
{
    const int e = blockIdx.x * 256 + threadIdx.x;
    if (e < E) atomicAdd(&deg[rowoff + edge[e + E]], 1);
}

__global__ __launch_bounds__(256)
void scan1_k(const int* __restrict__ in, int* __restrict__ out, int* __restrict__ bsum, int n)
{
    __shared__ int wsum[4];
    const int base = blockIdx.x * 2048 + threadIdx.x * 8;
    int v[8]; int t = 0;
    #pragma unroll
    for (int k = 0; k < 8; ++k) { const int idx = base + k; v[k] = (idx < n) ? in[idx] : 0; t += v[k]; }
    int sc = t;
    #pragma unroll
    for (int off = 1; off < 64; off <<= 1) {
        const int u = __shfl_up(sc, off, 64);
        if ((threadIdx.x & 63) >= off) sc += u;
    }
    const int w = threadIdx.x >> 6, lane = threadIdx.x & 63;
    if (lane == 63) wsum[w] = sc;
    __syncthreads();
    int woff = 0;
    for (int i = 0; i < w; ++i) woff += wsum[i];
    int run = sc - t + woff;
    #pragma unroll
    for (int k = 0; k < 8; ++k) {
        const int idx = base + k;
        run += v[k];
        if (idx < n) out[idx + 1] = run;
    }
    if (threadIdx.x == 255) bsum[blockIdx.x] = run;
}

__global__ void scan2_k(int* bsum, int nb)
{
    if (threadIdx.x == 0 && blockIdx.x == 0) {
        int acc = 0;
        for (int i = 0; i < nb; ++i) { acc += bsum[i]; bsum[i] = acc; }
    }
}

__global__ __launch_bounds__(256)
void scan3_k(int* __restrict__ rowptr, const int* __restrict__ bsum, int n)
{
    const int i = blockIdx.x * 256 + threadIdx.x;
    if (i == 0) rowptr[0] = 0;
    if (i < n) {
        const int b = i >> 11;
        if (b > 0) rowptr[i + 1] += bsum[b - 1];
    }
}

__global__ __launch_bounds__(256)
void fill_k(const int* __restrict__ edge, int E, const int* __restrict__ rowptr,
            int rowoff, int* __restrict__ next, int* __restrict__ colsrc)
{
    const int e = blockIdx.x * 256 + threadIdx.x;
    if (e >= E) return;
    const int s = edge[e], d = edge[e + E];
    const int p = atomicAdd(&next[rowoff + d], 1);
    colsrc[rowptr[rowoff + d] + p] = s;
}

// ---------------- CSR mean-aggregate, unroll-4 for memory-level parallelism ----------------
template<int C>
__global__ __launch_bounds__(256)
void aggc_k(const float* __restrict__ X, const int* __restrict__ rowptr,
            const int* __restrict__ colsrc, int rowoff, int n, float scale,
            float* __restrict__ out)
{
    const int wid  = (int)((blockIdx.x * 256 + threadIdx.x) >> 6);
    const int lane = threadIdx.x & 63;
    if (wid >= n) return;
    const int beg = rowptr[rowoff + wid], end = rowptr[rowoff + wid + 1];
    float a0 = 0.f, a1 = 0.f;
    int j = beg;
    for (; j + 4 <= end; j += 4) {
        const int s0 = colsrc[j], s1 = colsrc[j + 1], s2 = colsrc[j + 2], s3 = colsrc[j + 3];
        const float* p0 = X + (size_t)s0 * C;
        const float* p1 = X + (size_t)s1 * C;
        const float* p2 = X + (size_t)s2 * C;
        const float* p3 = X + (size_t)s3 * C;
        const float v00 = p0[lane], v10 = p1[lane], v20 = p2[lane], v30 = p3[lane];
        float v01 = 0.f, v11 = 0.f, v21 = 0.f, v31 = 0.f;
        if (C == 128) { v01 = p0[lane + 64]; v11 = p1[lane + 64]; v21 = p2[lane + 64]; v31 = p3[lane + 64]; }
        a0 += (v00 + v10) + (v20 + v30);
        if (C == 128) a1 += (v01 + v11) + (v21 + v31);
    }
    for (; j < end; ++j) {
        const float* p = X + (size_t)colsrc[j] * C;
        a0 += p[lane];
        if (C == 128) a1 += p[lane + 64];
    }
    const float m = scale / fmaxf((float)(end - beg), 1.0f);
    float* op = out + (size_t)wid * C;
    op[lane] = a0 * m;
    if (C == 128) op[lane + 64] = a1 * m;
}

// ---------------- Y (=|+=) scale * T/||T||  (C=128) ----------------
template<bool FIRST>
__global__ __launch_bounds__(256)
void l2acc_k(const float* __restrict__ T, float* __restrict__ Y, float scale, int n)
{
    const int wid  = (int)((blockIdx.x * 256 + threadIdx.x) >> 6);
    const int lane = threadIdx.x & 63;
    if (wid >= n) return;
    const float* t = T + (size_t)wid * 128;
    const float v0 = t[lane], v1 = t[lane + 64];
    float ss = v0 * v0 + v1 * v1;
    #pragma unroll
    for (int off = 32; off > 0; off >>= 1) ss += __shfl_xor(ss, off, 64);
    const float inv = scale / fmaxf(sqrtf(ss), 1e-12f);
    float* y = Y + (size_t)wid * 128;
    if (FIRST) {
        y[lane]      = v0 * inv;
        y[lane + 64] = v1 * inv;
    } else {
        y[lane]      += v0 * inv;
        y[lane + 64] += v1 * inv;
    }
}

// ---------------- in-place x = LayerNorm(relu(x)) * g + b  (C=128) ----------------
__global__ __launch_bounds__(256)
void relu_ln_k(float* __restrict__ X, const float* __restrict__ g,
               const float* __restrict__ b, int n)
{
    const int wid  = (int)((blockIdx.x * 256 + threadIdx.x) >> 6);
    const int lane = threadIdx.x & 63;
    if (wid >= n) return;
    float* x = X + (size_t)wid * 128;
    const float v0 = fmaxf(x[lane], 0.f), v1 = fmaxf(x[lane + 64], 0.f);
    float s = v0 + v1;
    #pragma unroll
    for (int off = 32; off > 0; off >>= 1) s += __shfl_xor(s, off, 64);
    const float m  = s * (1.0f / 128.0f);
    const float d0 = v0 - m, d1 = v1 - m;
    float vv = d0 * d0 + d1 * d1;
    #pragma unroll
    for (int off = 32; off > 0; off >>= 1) vv += __shfl_xor(vv, off, 64);
    const float inv = 1.0f / sqrtf(vv * (1.0f / 128.0f) + 1e-5f);
    x[lane]      = d0 * inv * g[lane]      + b[lane];
    x[lane + 64] = d1 * inv * g[lane + 64] + b[lane + 64];
}

// ---------------- merge Wr/bl across relations per (layer, dst-type) ----------------
__global__ void merge_k(const float* __restrict__ Wr, const float* __restrict__ bl,
                        float* __restrict__ Wm, float* __restrict__ bm)
{
    const int li = blockIdx.y >> 1, dt = blockIdx.y & 1;
    const int idx = blockIdx.x * 256 + threadIdx.x;          // 0..16383
    const float* Wb = Wr + (size_t)li * 5 * 16384;
    const float* bb = bl + (size_t)li * 5 * 128;
    float v;
    if (dt == 0)
        v = (Wb[0 * 16384 + idx] + Wb[1 * 16384 + idx] + Wb[3 * 16384 + idx]) * (1.0f / 3.0f);
    else
        v = (Wb[2 * 16384 + idx] + Wb[4 * 16384 + idx]) * 0.5f;
    Wm[(size_t)blockIdx.y * 16384 + idx] = v;
    if (blockIdx.x == 0 && threadIdx.x < 128) {
        const int c = threadIdx.x;
        const float bv = (dt == 0)
            ? (bb[0 * 128 + c] + bb[1 * 128 + c] + bb[3 * 128 + c]) * (1.0f / 3.0f)
            : (bb[2 * 128 + c] + bb[4 * 128 + c]) * 0.5f;
        bm[blockIdx.y * 128 + c] = bv;
    }
}

// ---------------- fold eval-mode BatchNorm into mlp_W2 / b2 ----------------
__global__ void headprep_k(const float* __restrict__ W2, const float* __restrict__ b2,
                           const float* __restrict__ bng, const float* __restrict__ bnb,
                           float* __restrict__ W2p, float* __restrict__ b2p)
{
    const int idx = blockIdx.x * 256 + threadIdx.x;
    const float is = 1.0f / sqrtf(1.0f + 1e-5f);
    if (idx < 128 * 32) {
        const int k = idx >> 5;
        W2p[idx] = W2[idx] * (bng[k] * is);
    }
    if (idx < 32) {
        float s = b2[idx];
        for (int k = 0; k < 128; ++k) s += bnb[k] * W2[k * 32 + idx];
        b2p[idx] = s;
    }
}

// ---------------- orchestration ----------------
extern "C" void kernel_launch(void* const* d_in, const int* in_sizes, int n_in,
                              void* d_out, int out_size, void* d_ws, size_t ws_size,
                              hipStream_t stream)
{
    (void)n_in; (void)out_size; (void)ws_size;

    const float* x_note = (const float*)d_in[0];
    const float* x_beat = (const float*)d_in[1];
    const int*   e_on   = (const int*)d_in[2];
    const int*   e_co   = (const int*)d_in[3];
    const int*   e_nb   = (const int*)d_in[4];
    const int*   e_bn   = (const int*)d_in[5];
    const int*   e_bb   = (const int*)d_in[6];
    const float* proj_W = (const float*)d_in[7];
    const float* proj_b = (const float*)d_in[8];
    const float* l0_Wl  = (const float*)d_in[9];
    const float* l0_bl  = (const float*)d_in[10];
    const float* l0_Wr  = (const float*)d_in[11];
    const float* Wl     = (const float*)d_in[12];
    const float* bl     = (const float*)d_in[13];
    const float* Wr     = (const float*)d_in[14];
    const float* ln_g   = (const float*)d_in[15];
    const float* ln_b   = (const float*)d_in[16];
    const float* W1     = (const float*)d_in[17];
    const float* b1     = (const float*)d_in[18];
    const float* bn_g   = (const float*)d_in[19];
    const float* bn_b   = (const float*)d_in[20];
    const float* W2     = (const float*)d_in[21];
    const float* b2     = (const float*)d_in[22];

    const int E_on = in_sizes[2] / 2, E_co = in_sizes[3] / 2, E_nb = in_sizes[4] / 2,
              E_bn = in_sizes[5] / 2, E_bb = in_sizes[6] / 2;
    const int ETOT = E_on + E_co + E_nb + E_bn + E_bb;

    // ---- workspace layout ----
    float* ws = (float*)d_ws;
    size_t off = 0;
    auto alloc = [&](size_t nf) { float* p = ws + off; off += (nf + 63) & ~(size_t)63; return p; };
    float* nA   = alloc((size_t)NN * 128);
    float* nB   = alloc((size_t)NN * 128);   // also 'tmp' (never live simultaneously)
    float* bA   = alloc((size_t)NB * 128);
    float* bB   = alloc((size_t)NB * 128);
    float* agg  = alloc((size_t)NN * 128);
    float* Wm   = alloc(4 * 128 * 128);
    float* bm   = alloc(4 * 128);
    float* W2p  = alloc(128 * 32);
    float* b2p  = alloc(64);
    int* rowptr = (int*)alloc(LTOT + 64);
    int* deg    = (int*)alloc(LTOT);
    int* colsrc = (int*)alloc(ETOT);
    int* bsum   = (int*)alloc(256);
    float* tmp  = nB;

    struct RelDesc { int r, s, d; const int* e; int E; int rowoff; };
    const RelDesc rels[5] = {
        {0, 0, 0, e_on, E_on, 0},
        {1, 0, 0, e_co, E_co, NN},
        {2, 0, 1, e_nb, E_nb, 2 * NN},
        {3, 1, 0, e_bn, E_bn, 2 * NN + NB},
        {4, 1, 1, e_bb, E_bb, 3 * NN + NB} };
    const int nsz[2] = {NN, NB};
    const float Rdiv[2] = {3.0f, 2.0f};

    // ---- build concatenated CSR (once per call; reused by all 3 layers) ----
    hipMemsetAsync(deg, 0, (size_t)LTOT * 4, stream);
    for (int ri = 0; ri < 5; ++ri)
        hist_k<<<(rels[ri].E + 255) / 256, 256, 0, stream>>>(rels[ri].e, rels[ri].E, deg, rels[ri].rowoff);
    const int NBLK = (LTOT + 2047) / 2048;
    scan1_k<<<NBLK, 256, 0, stream>>>(deg, rowptr, bsum, LTOT);
    scan2_k<<<1, 64, 0, stream>>>(bsum, NBLK);
    scan3_k<<<(LTOT + 255) / 256, 256, 0, stream>>>(rowptr, bsum, LTOT);
    hipMemsetAsync(deg, 0, (size_t)LTOT * 4, stream);  // reuse as fill cursor
    for (int ri = 0; ri < 5; ++ri)
        fill_k<<<(rels[ri].E + 255) / 256, 256, 0, stream>>>(rels[ri].e, rels[ri].E, rowptr,
                                                             rels[ri].rowoff, deg, colsrc);

    // ---- weight prep ----
    merge_k<<<dim3(64, 4), 256, 0, stream>>>(Wr, bl, Wm, bm);
    headprep_k<<<16, 256, 0, stream>>>(W2, b2, bn_g, bn_b, W2p, b2p);

    // ================= layer 0 (64 -> 128, per-relation l2norm) =================
    for (int ri = 0; ri < 5; ++ri) {
        const RelDesc& R = rels[ri];
        const float* xs = R.s == 0 ? x_note : x_beat;
        const float* xd = R.d == 0 ? x_note : x_beat;
        const int ns = nsz[R.s], nd = nsz[R.d];
        float* newd = R.d == 0 ? nA : bA;
        // ps = relu(xs @ proj_W[r] + proj_b[r])  -> tmp (ns x 64)
        gemm_k<64, 0, 64, 64, false, true, true><<<(ns + 63) / 64, 256, 0, stream>>>(
            xs, nullptr, proj_W + (size_t)R.r * 64 * 64, nullptr, proj_b + R.r * 64, tmp, ns);
        // agg = mean_{src} ps
        aggc_k<64><<<(nd + 3) / 4, 256, 0, stream>>>(tmp, rowptr, colsrc, R.rowoff, nd, 1.0f, agg);
        // o = [agg | xd] @ [Wl; Wr] + bl   (fused dual-A GEMM) -> tmp (nd x 128)
        gemm_k<64, 64, 128, 32, false, false, true><<<(nd + 31) / 32, 256, 0, stream>>>(
            agg, xd, l0_Wl + (size_t)R.r * 64 * 128, l0_Wr + (size_t)R.r * 64 * 128,
            l0_bl + R.r * 128, tmp, nd);
        // newd (=|+=) l2norm(tmp) / R_d
        if (ri == 0)
            l2acc_k<true><<<(nd + 3) / 4, 256, 0, stream>>>(tmp, newd, 1.0f / Rdiv[R.d], nd);
        else if (ri == 2)
            l2acc_k<true><<<(nd + 3) / 4, 256, 0, stream>>>(tmp, newd, 1.0f / Rdiv[R.d], nd);
        else
            l2acc_k<false><<<(nd + 3) / 4, 256, 0, stream>>>(tmp, newd, 1.0f / Rdiv[R.d], nd);
    }
    relu_ln_k<<<(NN + 3) / 4, 256, 0, stream>>>(nA, ln_g, ln_b, NN);
    relu_ln_k<<<(NB + 3) / 4, 256, 0, stream>>>(bA, ln_g, ln_b, NB);

    // ================= layers 1,2 (128 -> 128, merged self-term fused into first rel GEMM) ====
    for (int li = 0; li < 2; ++li) {
        float* cn  = li == 0 ? nA : nB;  float* nn  = li == 0 ? nB : nA;
        float* cb  = li == 0 ? bA : bB;  float* nb_ = li == 0 ? bB : bA;
        // ---- notes: rel0 (dual with self), rel1, rel3 accumulate ----
        aggc_k<128><<<(NN + 3) / 4, 256, 0, stream>>>(cn, rowptr, colsrc, 0, NN, 1.0f / 3.0f, agg);
        gemm_k<128, 128, 128, 32, false, false, true><<<(NN + 31) / 32, 256, 0, stream>>>(
            agg, cn, Wl + (size_t)(li * 5 + 0) * 16384, Wm + (size_t)(li * 2 + 0) * 16384,
            bm + (li * 2 + 0) * 128, nn, NN);
        aggc_k<128><<<(NN + 3) / 4, 256, 0, stream>>>(cn, rowptr, colsrc, NN, NN, 1.0f / 3.0f, agg);
        gemm_k<128, 0, 128, 32, true, false, false><<<(NN + 31) / 32, 256, 0, stream>>>(
            agg, nullptr, Wl + (size_t)(li * 5 + 1) * 16384, nullptr, nullptr, nn, NN);
        aggc_k<128><<<(NN + 3) / 4, 256, 0, stream>>>(cb, rowptr, colsrc, 2 * NN + NB, NN, 1.0f / 3.0f, agg);
        gemm_k<128, 0, 128, 32, true, false, false><<<(NN + 31) / 32, 256, 0, stream>>>(
            agg, nullptr, Wl + (size_t)(li * 5 + 3) * 16384, nullptr, nullptr, nn, NN);
        // ---- beats: rel2 (dual with self), rel4 accumulate ----
        aggc_k<128><<<(NB + 3) / 4, 256, 0, stream>>>(cn, rowptr, colsrc, 2 * NN, NB, 0.5f, agg);
        gemm_k<128, 128, 128, 32, false, false, true><<<(NB + 31) / 32, 256, 0, stream>>>(
            agg, cb, Wl + (size_t)(li * 5 + 2) * 16384, Wm + (size_t)(li * 2 + 1) * 16384,
            bm + (li * 2 + 1) * 128, nb_, NB);
        aggc_k<128><<<(NB + 3) / 4, 256, 0, stream>>>(cb, rowptr, colsrc, 3 * NN + NB, NB, 0.5f, agg);
        gemm_k<128, 0, 128, 32, true, false, false><<<(NB + 31) / 32, 256, 0, stream>>>(
            agg, nullptr, Wl + (size_t)(li * 5 + 4) * 16384, nullptr, nullptr, nb_, NB);
        if (li == 0) {
            relu_ln_k<<<(NN + 3) / 4, 256, 0, stream>>>(nn,  ln_g + 128, ln_b + 128, NN);
            relu_ln_k<<<(NB + 3) / 4, 256, 0, stream>>>(nb_, ln_g + 128, ln_b + 128, NB);
        }
    }

    // ================= head: out = relu(note @ W1 + b1) @ W2p + b2p =================
    gemm_k<128, 0, 128, 32, false, true, true><<<(NN + 31) / 32, 256, 0, stream>>>(
        nA, nullptr, W1, nullptr, b1, tmp, NN);
    gemm_k<128, 0, 32, 32, false, false, true><<<(NN + 31) / 32, 256, 0, stream>>>(
        tmp, nullptr, W2p, nullptr, b2p, (float*)d_out, NN);
}

// Round 4
// 1184.919 us; speedup vs baseline: 6.0702x; 1.6088x over previous
//
#include <hip/hip_runtime.h>
#include <math.h>

typedef unsigned int   u32;
typedef unsigned short u16;
typedef short   short8 __attribute__((ext_vector_type(8)));
typedef float   f32x4  __attribute__((ext_vector_type(4)));

// ---------------- problem constants ----------------
constexpr int NN = 100000;   // note nodes
constexpr int NB = 20000;    // beat nodes
constexpr int LTOT = 3 * NN + 2 * NB;  // concatenated CSR rows

// ---------------- bf16 helpers (storage = unsigned short) ----------------
__device__ inline float blo(u32 u) { union { u32 i; float f; } v; v.i = u << 16;        return v.f; }
__device__ inline float bhi(u32 u) { union { u32 i; float f; } v; v.i = u & 0xffff0000u; return v.f; }
__device__ inline float b2f(u16 h) { union { u32 i; float f; } v; v.i = (u32)h << 16;   return v.f; }
__device__ inline u16  f2b(float f)
{ union { float f; u32 u; } v; v.f = f; return (u16)((v.u + 0x7fffu + ((v.u >> 16) & 1u)) >> 16); }

// ---------------- MFMA GEMM: Y = [Yin +] [A1|A2] @ [W1;W2] [+ bias] [relu] ----------------
// A1: n x K1 bf16, A2: n x K2 bf16 (row-major), W1: K1 x C bf16, W2: K2 x C bf16.
// Yin: n x C f32 (read iff ACC). Yout: n x C (f32 or bf16 per OUTBF16).
// LDS: A tile [BM][64] bf16 and W^T [C][64] bf16, both XOR-swizzled byte^=((row&7)<<4)
// (the verified G4 swizzle for 128B-stride rows). MFMA 16x16x32 bf16, fp32 accum.
// Wave grid: WVM x WVN waves; per wave RT2=2 row-tiles x CT col-tiles of 16x16.
template<int K1, int K2, int C, bool ACC, bool RELU, bool BIAS, bool OUTBF16>
__global__ __launch_bounds__(256)
void gemm16_k(const u16* __restrict__ A1, const u16* __restrict__ A2,
              const u16* __restrict__ W1, const u16* __restrict__ W2,
              const float* __restrict__ bias, const float* __restrict__ Yin,
              void* __restrict__ Yout, int n)
{
    constexpr int K   = K1 + K2;
    constexpr int NKB = K / 64;
    constexpr int WVN = (C >= 64) ? 2 : 1;   // waves along N
    constexpr int WVM = 4 / WVN;             // waves along M
    constexpr int RT2 = 2;                   // 16-row tiles per wave
    constexpr int BM  = WVM * RT2 * 16;      // 64 (C>=64) or 128 (C=32)
    constexpr int CT  = C / (WVN * 16);      // col tiles per wave
    static_assert(K1 % 64 == 0 && (K2 == 0 || K2 % 64 == 0), "K multiple of 64");

    __shared__ uint4 sA[BM * 8];   // [BM][64] bf16, uint4 idx = (row*8+k8)^(row&7)
    __shared__ uint4 sW[C * 8];    // [C][64] bf16 (W transposed), same swizzle

    const int tid  = threadIdx.x;
    const int lane = tid & 63;
    const int wv   = tid >> 6;
    const int wm   = wv % WVM;
    const int wn   = wv / WVM;
    const int lrow = lane & 15;
    const int lk8  = lane >> 4;
    const int row0 = blockIdx.x * BM;

    f32x4 acc[RT2][CT];
    #pragma unroll
    for (int rt = 0; rt < RT2; ++rt)
        #pragma unroll
        for (int ct = 0; ct < CT; ++ct) acc[rt][ct] = (f32x4){0.f, 0.f, 0.f, 0.f};

    for (int kb = 0; kb < NKB; ++kb) {
        if (kb) __syncthreads();
        const bool useA1 = (K2 == 0) || (kb * 64 < K1);
        // ---- stage A tile: BM*8 uint4 units ----
        {
            const u16* Asel   = useA1 ? A1 : A2;
            const int astride = useA1 ? K1 : K2;
            const int aoff    = useA1 ? kb * 64 : kb * 64 - K1;
            for (int u = tid; u < BM * 8; u += 256) {
                const int r  = u >> 3, k8 = u & 7;
                const int row = row0 + r;
                uint4 v = make_uint4(0u, 0u, 0u, 0u);
                if (row < n)
                    v = *reinterpret_cast<const uint4*>(Asel + (size_t)row * astride + aoff + k8 * 8);
                sA[(r * 8 + k8) ^ (r & 7)] = v;
            }
        }
        // ---- stage W^T: 64*(C/8) units; unit u: kk=u%64 (bank-spread), c8=(u/64)*8 ----
        {
            const u16* Wsel = useA1 ? W1 : W2;
            const int  goff = useA1 ? kb * 64 : kb * 64 - K1;
            u16* sWu = (u16*)sW;
            for (int u = tid; u < 64 * (C / 8); u += 256) {
                const int kk = u & 63, c8 = (u >> 6) * 8;
                const uint4 v = *reinterpret_cast<const uint4*>(Wsel + (size_t)(goff + kk) * C + c8);
                const u16* e = (const u16*)&v;
                #pragma unroll
                for (int j = 0; j < 8; ++j) {
                    const int c = c8 + j;
                    sWu[(c * 64 + kk) ^ ((c & 7) << 3)] = e[j];
                }
            }
        }
        __syncthreads();
        // ---- compute: 2 k-steps of 32 per chunk ----
        #pragma unroll
        for (int ks = 0; ks < 2; ++ks) {
            short8 af[RT2];
            #pragma unroll
            for (int rt = 0; rt < RT2; ++rt) {
                const int r = (wm * RT2 + rt) * 16 + lrow;
                af[rt] = *reinterpret_cast<const short8*>(&sA[(r * 8 + ks * 4 + lk8) ^ (lrow & 7)]);
            }
            #pragma unroll
            for (int ct = 0; ct < CT; ++ct) {
                const int c = (wn * CT + ct) * 16 + lrow;
                const short8 bfr = *reinterpret_cast<const short8*>(&sW[(c * 8 + ks * 4 + lk8) ^ (lrow & 7)]);
                #pragma unroll
                for (int rt = 0; rt < RT2; ++rt)
                    acc[rt][ct] = __builtin_amdgcn_mfma_f32_16x16x32_bf16(af[rt], bfr, acc[rt][ct], 0, 0, 0);
            }
        }
    }
    // ---- epilogue: C/D layout col=lane&15, row=(lane>>4)*4+reg ----
    #pragma unroll
    for (int ct = 0; ct < CT; ++ct) {
        const int colg = (wn * CT + ct) * 16 + lrow;
        const float bs = BIAS ? bias[colg] : 0.f;
        #pragma unroll
        for (int rt = 0; rt < RT2; ++rt) {
            const int rbase = row0 + (wm * RT2 + rt) * 16 + lk8 * 4;
            #pragma unroll
            for (int r = 0; r < 4; ++r) {
                const int row = rbase + r;
                if (row >= n) continue;
                float v = acc[rt][ct][r] + bs;
                if (ACC)  v += Yin[(size_t)row * C + colg];
                if (RELU) v = fmaxf(v, 0.f);
                if (OUTBF16) ((u16*)Yout)[(size_t)row * C + colg] = f2b(v);
                else         ((float*)Yout)[(size_t)row * C + colg] = v;
            }
        }
    }
}

// ---------------- CSR build ----------------
__global__ __launch_bounds__(256)
void hist_k(const int* __restrict__ edge, int E, int* __restrict__ deg, int rowoff)
{
    const int e = blockIdx.x * 256 + threadIdx.x;
    if (e < E) atomicAdd(&deg[rowoff + edge[e + E]], 1);
}

__global__ __launch_bounds__(256)
void scan1_k(const int* __restrict__ in, int* __restrict__ out, int* __restrict__ bsum, int n)
{
    __shared__ int wsum[4];
    const int base = blockIdx.x * 2048 + threadIdx.x * 8;
    int v[8]; int t = 0;
    #pragma unroll
    for (int k = 0; k < 8; ++k) { const int idx = base + k; v[k] = (idx < n) ? in[idx] : 0; t += v[k]; }
    int sc = t;
    #pragma unroll
    for (int off = 1; off < 64; off <<= 1) {
        const int u = __shfl_up(sc, off, 64);
        if ((threadIdx.x & 63) >= off) sc += u;
    }
    const int w = threadIdx.x >> 6, lane = threadIdx.x & 63;
    if (lane == 63) wsum[w] = sc;
    __syncthreads();
    int woff = 0;
    for (int i = 0; i < w; ++i) woff += wsum[i];
    int run = sc - t + woff;
    #pragma unroll
    for (int k = 0; k < 8; ++k) {
        const int idx = base + k;
        run += v[k];
        if (idx < n) out[idx + 1] = run;
    }
    if (threadIdx.x == 255) bsum[blockIdx.x] = run;
}

__global__ void scan2_k(int* bsum, int nb)
{
    if (threadIdx.x == 0 && blockIdx.x == 0) {
        int acc = 0;
        for (int i = 0; i < nb; ++i) { acc += bsum[i]; bsum[i] = acc; }
    }
}

__global__ __launch_bounds__(256)
void scan3_k(int* __restrict__ rowptr, const int* __restrict__ bsum, int n)
{
    const int i = blockIdx.x * 256 + threadIdx.x;
    if (i == 0) rowptr[0] = 0;
    if (i < n) {
        const int b = i >> 11;
        if (b > 0) rowptr[i + 1] += bsum[b - 1];
    }
}

__global__ __launch_bounds__(256)
void fill_k(const int* __restrict__ edge, int E, const int* __restrict__ rowptr,
            int rowoff, int* __restrict__ next, int* __restrict__ colsrc)
{
    const int e = blockIdx.x * 256 + threadIdx.x;
    if (e >= E) return;
    const int s = edge[e], d = edge[e + E];
    const int p = atomicAdd(&next[rowoff + d], 1);
    colsrc[rowptr[rowoff + d] + p] = s;
}

// ---------------- CSR mean-aggregate (bf16 in/out, f32 sums), unroll-4 ----------------
__global__ __launch_bounds__(256)
void aggc16_128_k(const u16* __restrict__ X, const int* __restrict__ rowptr,
                  const int* __restrict__ colsrc, int rowoff, int n, float scale,
                  u16* __restrict__ out)
{
    const int wid  = (int)((blockIdx.x * 256 + threadIdx.x) >> 6);
    const int lane = threadIdx.x & 63;
    if (wid >= n) return;
    const int beg = rowptr[rowoff + wid], end = rowptr[rowoff + wid + 1];
    const u32* Xu = (const u32*)X;
    float a0 = 0.f, a1 = 0.f;
    int j = beg;
    for (; j + 4 <= end; j += 4) {
        const int s0 = colsrc[j], s1 = colsrc[j + 1], s2 = colsrc[j + 2], s3 = colsrc[j + 3];
        const u32 u0 = Xu[(size_t)s0 * 64 + lane], u1 = Xu[(size_t)s1 * 64 + lane];
        const u32 u2 = Xu[(size_t)s2 * 64 + lane], u3 = Xu[(size_t)s3 * 64 + lane];
        a0 += (blo(u0) + blo(u1)) + (blo(u2) + blo(u3));
        a1 += (bhi(u0) + bhi(u1)) + (bhi(u2) + bhi(u3));
    }
    for (; j < end; ++j) {
        const u32 u = Xu[(size_t)colsrc[j] * 64 + lane];
        a0 += blo(u); a1 += bhi(u);
    }
    const float m = scale / fmaxf((float)(end - beg), 1.0f);
    ((u32*)out)[(size_t)wid * 64 + lane] = (u32)f2b(a0 * m) | ((u32)f2b(a1 * m) << 16);
}

__global__ __launch_bounds__(256)
void aggc16_64_k(const u16* __restrict__ X, const int* __restrict__ rowptr,
                 const int* __restrict__ colsrc, int rowoff, int n, float scale,
                 u16* __restrict__ out)
{
    const int wid  = (int)((blockIdx.x * 256 + threadIdx.x) >> 6);
    const int lane = threadIdx.x & 63;
    if (wid >= n) return;
    const int beg = rowptr[rowoff + wid], end = rowptr[rowoff + wid + 1];
    float a0 = 0.f;
    int j = beg;
    for (; j + 4 <= end; j += 4) {
        const int s0 = colsrc[j], s1 = colsrc[j + 1], s2 = colsrc[j + 2], s3 = colsrc[j + 3];
        const float v0 = b2f(X[(size_t)s0 * 64 + lane]), v1 = b2f(X[(size_t)s1 * 64 + lane]);
        const float v2 = b2f(X[(size_t)s2 * 64 + lane]), v3 = b2f(X[(size_t)s3 * 64 + lane]);
        a0 += (v0 + v1) + (v2 + v3);
    }
    for (; j < end; ++j) a0 += b2f(X[(size_t)colsrc[j] * 64 + lane]);
    const float m = scale / fmaxf((float)(end - beg), 1.0f);
    out[(size_t)wid * 64 + lane] = f2b(a0 * m);
}

// ---------------- Y (=|+=) scale * T/||T||, T f32 n x 128 ----------------
template<bool FIRST>
__global__ __launch_bounds__(256)
void l2acc_k(const float* __restrict__ T, float* __restrict__ Y, float scale, int n)
{
    const int wid  = (int)((blockIdx.x * 256 + threadIdx.x) >> 6);
    const int lane = threadIdx.x & 63;
    if (wid >= n) return;
    const float* t = T + (size_t)wid * 128;
    const float v0 = t[lane], v1 = t[lane + 64];
    float ss = v0 * v0 + v1 * v1;
    #pragma unroll
    for (int off = 32; off > 0; off >>= 1) ss += __shfl_xor(ss, off, 64);
    const float inv = scale / fmaxf(sqrtf(ss), 1e-12f);
    float* y = Y + (size_t)wid * 128;
    if (FIRST) { y[lane] = v0 * inv;  y[lane + 64] = v1 * inv; }
    else       { y[lane] += v0 * inv; y[lane + 64] += v1 * inv; }
}

// ---------------- OUT(bf16) = LayerNorm(relu(X)) * g + b, X f32 n x 128 ----------------
__global__ __launch_bounds__(256)
void relu_ln16_k(const float* __restrict__ X, const float* __restrict__ g,
                 const float* __restrict__ b, u16* __restrict__ OUT, int n)
{
    const int wid  = (int)((blockIdx.x * 256 + threadIdx.x) >> 6);
    const int lane = threadIdx.x & 63;
    if (wid >= n) return;
    const float* x = X + (size_t)wid * 128;
    const float v0 = fmaxf(x[lane], 0.f), v1 = fmaxf(x[lane + 64], 0.f);
    float s = v0 + v1;
    #pragma unroll
    for (int off = 32; off > 0; off >>= 1) s += __shfl_xor(s, off, 64);
    const float m  = s * (1.0f / 128.0f);
    const float d0 = v0 - m, d1 = v1 - m;
    float vv = d0 * d0 + d1 * d1;
    #pragma unroll
    for (int off = 32; off > 0; off >>= 1) vv += __shfl_xor(vv, off, 64);
    const float inv = 1.0f / sqrtf(vv * (1.0f / 128.0f) + 1e-5f);
    OUT[(size_t)wid * 128 + lane]      = f2b(d0 * inv * g[lane]      + b[lane]);
    OUT[(size_t)wid * 128 + lane + 64] = f2b(d1 * inv * g[lane + 64] + b[lane + 64]);
}

// ---------------- merge Wr/bl across relations -> bf16 Wm, f32 bm ----------------
__global__ void merge_k(const float* __restrict__ Wr, const float* __restrict__ bl,
                        u16* __restrict__ Wm16, float* __restrict__ bm)
{
    const int li = blockIdx.y >> 1, dt = blockIdx.y & 1;
    const int idx = blockIdx.x * 256 + threadIdx.x;          // 0..16383
    const float* Wb = Wr + (size_t)li * 5 * 16384;
    const float* bb = bl + (size_t)li * 5 * 128;
    float v;
    if (dt == 0)
        v = (Wb[idx] + Wb[16384 + idx] + Wb[3 * 16384 + idx]) * (1.0f / 3.0f);
    else
        v = (Wb[2 * 16384 + idx] + Wb[4 * 16384 + idx]) * 0.5f;
    Wm16[(size_t)blockIdx.y * 16384 + idx] = f2b(v);
    if (blockIdx.x == 0 && threadIdx.x < 128) {
        const int c = threadIdx.x;
        const float bv = (dt == 0)
            ? (bb[c] + bb[128 + c] + bb[3 * 128 + c]) * (1.0f / 3.0f)
            : (bb[2 * 128 + c] + bb[4 * 128 + c]) * 0.5f;
        bm[blockIdx.y * 128 + c] = bv;
    }
}

// ---------------- fold eval-mode BatchNorm into W2/b2 -> bf16 W2p, f32 b2p ----------------
__global__ void headprep_k(const float* __restrict__ W2, const float* __restrict__ b2,
                           const float* __restrict__ bng, const float* __restrict__ bnb,
                           u16* __restrict__ W2p16, float* __restrict__ b2p)
{
    const int idx = blockIdx.x * 256 + threadIdx.x;
    const float is = 1.0f / sqrtf(1.0f + 1e-5f);
    if (idx < 128 * 32) {
        const int k = idx >> 5;
        W2p16[idx] = f2b(W2[idx] * (bng[k] * is));
    }
    if (idx < 32) {
        float s = b2[idx];
        for (int k = 0; k < 128; ++k) s += bnb[k] * W2[k * 32 + idx];
        b2p[idx] = s;
    }
}

// ---------------- batched f32 -> bf16 casts ----------------
struct CastJobs { const float* s[7]; u16* d[7]; int n[7]; };
__global__ __launch_bounds__(256)
void castmany_k(CastJobs J)
{
    const int j = blockIdx.y;
    const float* s = J.s[j]; u16* d = J.d[j]; const int n = J.n[j];
    for (int i = blockIdx.x * 256 + threadIdx.x; i < n; i += gridDim.x * 256)
        d[i] = f2b(s[i]);
}

// ---------------- orchestration ----------------
extern "C" void kernel_launch(void* const* d_in, const int* in_sizes, int n_in,
                              void* d_out, int out_size, void* d_ws, size_t ws_size,
                              hipStream_t stream)
{
    (void)n_in; (void)out_size; (void)ws_size;

    const float* x_note = (const float*)d_in[0];
    const float* x_beat = (const float*)d_in[1];
    const int*   e_on   = (const int*)d_in[2];
    const int*   e_co   = (const int*)d_in[3];
    const int*   e_nb   = (const int*)d_in[4];
    const int*   e_bn   = (const int*)d_in[5];
    const int*   e_bb   = (const int*)d_in[6];
    const float* proj_W = (const float*)d_in[7];
    const float* proj_b = (const float*)d_in[8];
    const float* l0_Wl  = (const float*)d_in[9];
    const float* l0_bl  = (const float*)d_in[10];
    const float* l0_Wr  = (const float*)d_in[11];
    const float* Wl     = (const float*)d_in[12];
    const float* bl     = (const float*)d_in[13];
    const float* Wr     = (const float*)d_in[14];
    const float* ln_g   = (const float*)d_in[15];
    const float* ln_b   = (const float*)d_in[16];
    const float* W1     = (const float*)d_in[17];
    const float* b1     = (const float*)d_in[18];
    const float* bn_g   = (const float*)d_in[19];
    const float* bn_b   = (const float*)d_in[20];
    const float* W2     = (const float*)d_in[21];
    const float* b2     = (const float*)d_in[22];

    const int E_on = in_sizes[2] / 2, E_co = in_sizes[3] / 2, E_nb = in_sizes[4] / 2,
              E_bn = in_sizes[5] / 2, E_bb = in_sizes[6] / 2;
    const int ETOT = E_on + E_co + E_nb + E_bn + E_bb;

    // ---- workspace layout ----
    char* wsb = (char*)d_ws;
    size_t off = 0;
    auto alloc = [&](size_t bytes) { char* p = wsb + off; off += (bytes + 255) & ~(size_t)255; return p; };
    float* tmpF  = (float*)alloc((size_t)NN * 128 * 4);   // per-rel dual output (f32)
    float* nF    = (float*)alloc((size_t)NN * 128 * 4);   // f32 note accum / GEMM out
    float* bF    = (float*)alloc((size_t)NB * 128 * 4);   // f32 beat accum / GEMM out
    u16*  n16    = (u16*)alloc((size_t)NN * 128 * 2);     // note features bf16 (layers 0,1)
    u16*  b16    = (u16*)alloc((size_t)NB * 128 * 2);     // beat features bf16
    u16*  n16h   = (u16*)alloc((size_t)NN * 128 * 2);     // layer-2 note out bf16
    u16*  agg16  = (u16*)alloc((size_t)NN * 128 * 2);     // aggregated neighbors bf16
    u16*  xn16   = n16;                                    // alias: x_note bf16 (layer-0 only)
    u16*  xb16   = b16;                                    // alias: x_beat bf16 (layer-0 only)
    u16*  proj16 = n16h;                                   // alias: proj output bf16 (layer-0 only)
    u16*  tmp16h = agg16;                                  // alias: head hidden bf16
    u16*  projW16 = (u16*)alloc(5 * 64 * 64 * 2);
    u16*  l0Wl16  = (u16*)alloc(5 * 64 * 128 * 2);
    u16*  l0Wr16  = (u16*)alloc(5 * 64 * 128 * 2);
    u16*  Wl16    = (u16*)alloc(2 * 5 * 128 * 128 * 2);
    u16*  W116    = (u16*)alloc(128 * 128 * 2);
    u16*  Wm16    = (u16*)alloc(4 * 128 * 128 * 2);
    u16*  W2p16   = (u16*)alloc(128 * 32 * 2);
    float* bm     = (float*)alloc(4 * 128 * 4);
    float* b2p    = (float*)alloc(32 * 4);
    int* rowptr = (int*)alloc((LTOT + 64) * 4);
    int* deg    = (int*)alloc(LTOT * 4);
    int* colsrc = (int*)alloc((size_t)ETOT * 4);
    int* bsum   = (int*)alloc(256 * 4);

    struct RelDesc { int r, s, d; const int* e; int E; int rowoff; };
    const RelDesc rels[5] = {
        {0, 0, 0, e_on, E_on, 0},
        {1, 0, 0, e_co, E_co, NN},
        {2, 0, 1, e_nb, E_nb, 2 * NN},
        {3, 1, 0, e_bn, E_bn, 2 * NN + NB},
        {4, 1, 1, e_bb, E_bb, 3 * NN + NB} };
    const int nsz[2] = {NN, NB};
    const float Rdiv[2] = {3.0f, 2.0f};

    // ---- build concatenated CSR (reused by all 3 layers) ----
    hipMemsetAsync(deg, 0, (size_t)LTOT * 4, stream);
    for (int ri = 0; ri < 5; ++ri)
        hist_k<<<(rels[ri].E + 255) / 256, 256, 0, stream>>>(rels[ri].e, rels[ri].E, deg, rels[ri].rowoff);
    const int NBLK = (LTOT + 2047) / 2048;
    scan1_k<<<NBLK, 256, 0, stream>>>(deg, rowptr, bsum, LTOT);
    scan2_k<<<1, 64, 0, stream>>>(bsum, NBLK);
    scan3_k<<<(LTOT + 255) / 256, 256, 0, stream>>>(rowptr, bsum, LTOT);
    hipMemsetAsync(deg, 0, (size_t)LTOT * 4, stream);
    for (int ri = 0; ri < 5; ++ri)
        fill_k<<<(rels[ri].E + 255) / 256, 256, 0, stream>>>(rels[ri].e, rels[ri].E, rowptr,
                                                             rels[ri].rowoff, deg, colsrc);

    // ---- weight prep + input casts ----
    merge_k<<<dim3(64, 4), 256, 0, stream>>>(Wr, bl, Wm16, bm);
    headprep_k<<<16, 256, 0, stream>>>(W2, b2, bn_g, bn_b, W2p16, b2p);
    {
        CastJobs J;
        J.s[0] = x_note; J.d[0] = xn16;    J.n[0] = NN * 64;
        J.s[1] = x_beat; J.d[1] = xb16;    J.n[1] = NB * 64;
        J.s[2] = proj_W; J.d[2] = projW16; J.n[2] = 5 * 64 * 64;
        J.s[3] = l0_Wl;  J.d[3] = l0Wl16;  J.n[3] = 5 * 64 * 128;
        J.s[4] = l0_Wr;  J.d[4] = l0Wr16;  J.n[4] = 5 * 64 * 128;
        J.s[5] = Wl;     J.d[5] = Wl16;    J.n[5] = 2 * 5 * 128 * 128;
        J.s[6] = W1;     J.d[6] = W116;    J.n[6] = 128 * 128;
        castmany_k<<<dim3(512, 7), 256, 0, stream>>>(J);
    }

    // ================= layer 0 (64 -> 128, per-relation l2norm) =================
    for (int ri = 0; ri < 5; ++ri) {
        const RelDesc& R = rels[ri];
        const u16* xs = R.s == 0 ? xn16 : xb16;
        const u16* xd = R.d == 0 ? xn16 : xb16;
        const int ns = nsz[R.s], nd = nsz[R.d];
        float* accum = R.d == 0 ? nF : bF;
        // proj16 = relu(xs @ proj_W[r] + proj_b[r])   (bf16 out, ns x 64)
        gemm16_k<64, 0, 64, false, true, true, true><<<(ns + 63) / 64, 256, 0, stream>>>(
            xs, nullptr, projW16 + (size_t)R.r * 4096, nullptr, proj_b + R.r * 64, nullptr, proj16, ns);
        // agg16 = mean_{src} proj16  (bf16, nd x 64)
        aggc16_64_k<<<(nd + 3) / 4, 256, 0, stream>>>(proj16, rowptr, colsrc, R.rowoff, nd, 1.0f, agg16);
        // tmpF = [agg16 | xd] @ [Wl; Wr] + bl   (f32 out, nd x 128)
        gemm16_k<64, 64, 128, false, false, true, false><<<(nd + 63) / 64, 256, 0, stream>>>(
            agg16, xd, l0Wl16 + (size_t)R.r * 8192, l0Wr16 + (size_t)R.r * 8192,
            l0_bl + R.r * 128, nullptr, tmpF, nd);
        // accum (=|+=) l2norm(tmpF) / R_d
        if (ri == 0 || ri == 2)
            l2acc_k<true><<<(nd + 3) / 4, 256, 0, stream>>>(tmpF, accum, 1.0f / Rdiv[R.d], nd);
        else
            l2acc_k<false><<<(nd + 3) / 4, 256, 0, stream>>>(tmpF, accum, 1.0f / Rdiv[R.d], nd);
    }
    relu_ln16_k<<<(NN + 3) / 4, 256, 0, stream>>>(nF, ln_g, ln_b, n16, NN);   // overwrites xn16 alias (done with x)
    relu_ln16_k<<<(NB + 3) / 4, 256, 0, stream>>>(bF, ln_g, ln_b, b16, NB);

    // ================= layers 1,2 (128 -> 128); layer 2 skips beats (unused) ======
    for (int li = 0; li < 2; ++li) {
        const u16* Wlb = Wl16 + (size_t)li * 5 * 16384;
        // ---- notes: rel0 dual (agg | self), rel1 ACC, rel3 ACC ----
        aggc16_128_k<<<(NN + 3) / 4, 256, 0, stream>>>(n16, rowptr, colsrc, 0, NN, 1.0f / 3.0f, agg16);
        gemm16_k<128, 128, 128, false, false, true, false><<<(NN + 63) / 64, 256, 0, stream>>>(
            agg16, n16, Wlb, Wm16 + (size_t)(li * 2) * 16384, bm + (li * 2) * 128, nullptr, nF, NN);
        aggc16_128_k<<<(NN + 3) / 4, 256, 0, stream>>>(n16, rowptr, colsrc, NN, NN, 1.0f / 3.0f, agg16);
        gemm16_k<128, 0, 128, true, false, false, false><<<(NN + 63) / 64, 256, 0, stream>>>(
            agg16, nullptr, Wlb + 16384, nullptr, nullptr, nF, nF, NN);
        aggc16_128_k<<<(NN + 3) / 4, 256, 0, stream>>>(b16, rowptr, colsrc, 2 * NN + NB, NN, 1.0f / 3.0f, agg16);
        if (li == 0) {
            gemm16_k<128, 0, 128, true, false, false, false><<<(NN + 63) / 64, 256, 0, stream>>>(
                agg16, nullptr, Wlb + 3 * 16384, nullptr, nullptr, nF, nF, NN);
            // ---- beats: rel2 dual (agg | self), rel4 ACC ----
            aggc16_128_k<<<(NB + 3) / 4, 256, 0, stream>>>(n16, rowptr, colsrc, 2 * NN, NB, 0.5f, agg16);
            gemm16_k<128, 128, 128, false, false, true, false><<<(NB + 63) / 64, 256, 0, stream>>>(
                agg16, b16, Wlb + 2 * 16384, Wm16 + (size_t)(li * 2 + 1) * 16384,
                bm + (li * 2 + 1) * 128, nullptr, bF, NB);
            aggc16_128_k<<<(NB + 3) / 4, 256, 0, stream>>>(b16, rowptr, colsrc, 3 * NN + NB, NB, 0.5f, agg16);
            gemm16_k<128, 0, 128, true, false, false, false><<<(NB + 63) / 64, 256, 0, stream>>>(
                agg16, nullptr, Wlb + 4 * 16384, nullptr, nullptr, bF, bF, NB);
            relu_ln16_k<<<(NN + 3) / 4, 256, 0, stream>>>(nF, ln_g + 128, ln_b + 128, n16, NN);
            relu_ln16_k<<<(NB + 3) / 4, 256, 0, stream>>>(bF, ln_g + 128, ln_b + 128, b16, NB);
        } else {
            // layer 2: final note ACC-GEMM emits bf16 directly into n16h; beats skipped
            gemm16_k<128, 0, 128, true, false, false, true><<<(NN + 63) / 64, 256, 0, stream>>>(
                agg16, nullptr, Wlb + 3 * 16384, nullptr, nullptr, nF, n16h, NN);
        }
    }

    // ================= head: out = relu(note @ W1 + b1) @ W2p + b2p =================
    gemm16_k<128, 0, 128, false, true, true, true><<<(NN + 63) / 64, 256, 0, stream>>>(
        n16h, nullptr, W116, nullptr, b1, nullptr, tmp16h, NN);
    gemm16_k<128, 0, 32, false, false, true, false><<<(NN + 127) / 128, 256, 0, stream>>>(
        tmp16h, nullptr, W2p16, nullptr, b2p, nullptr, d_out, NN);
}

// Round 6
// 913.224 us; speedup vs baseline: 7.8761x; 1.2975x over previous
//
#include <hip/hip_runtime.h>
#include <math.h>

typedef unsigned int   u32;
typedef unsigned short u16;
typedef short   short8 __attribute__((ext_vector_type(8)));
typedef float   f32x4  __attribute__((ext_vector_type(4)));

// ---------------- problem constants ----------------
constexpr int NN = 100000;   // note nodes
constexpr int NB = 20000;    // beat nodes
constexpr int LTOT = 3 * NN + 2 * NB;  // concatenated CSR rows

// ---------------- bf16 helpers ----------------
__device__ inline float blo(u32 u) { union { u32 i; float f; } v; v.i = u << 16;        return v.f; }
__device__ inline float bhi(u32 u) { union { u32 i; float f; } v; v.i = u & 0xffff0000u; return v.f; }
__device__ inline u16  f2b(float f)
{ union { float f; u32 u; } v; v.f = f; return (u16)((v.u + 0x7fffu + ((v.u >> 16) & 1u)) >> 16); }

// ---------------- MFMA GEMM with fused epilogues ----------------
// Y = epi( [A1|A2] @ W + bias )
// A1: n x K1 bf16, A2: n x K2 bf16, W: (K1+K2) x C bf16 (row-major).
// EPI: 0 f32->Yf | 1 bf16->Yh | 2 relu bf16->Yh
//      3 l2norm*scale ->Yf (=) | 4 l2norm*scale ->Yf (+=) | 5 relu+LayerNorm(g,b) bf16->Yh
// LDS: A tile [BM][64] + W^T [C][64], both XOR-swizzled (verified G4 swizzle).
template<int K1, int K2, int C, int EPI, bool BIAS>
__global__ __launch_bounds__(256)
void gemm16_k(const u16* __restrict__ A1, const u16* __restrict__ A2,
              const u16* __restrict__ W, const float* __restrict__ bias,
              const float* __restrict__ g, const float* __restrict__ bvec,
              float scale, float* __restrict__ Yf, u16* __restrict__ Yh, int n)
{
    constexpr int K   = K1 + K2;
    constexpr int NKB = K / 64;
    constexpr int WVN = (C >= 64) ? 2 : 1;
    constexpr int WVM = 4 / WVN;
    constexpr int RT2 = 2;
    constexpr int BM  = WVM * RT2 * 16;
    constexpr int CT  = C / (WVN * 16);
    static_assert(K1 % 64 == 0 && (K2 == 0 || K2 % 64 == 0), "K multiple of 64");

    __shared__ uint4 sA[BM * 8];
    __shared__ uint4 sW[C * 8];
    __shared__ float redS[2][BM];
    __shared__ float redQ[2][BM];

    const int tid  = threadIdx.x;
    const int lane = tid & 63;
    const int wv   = tid >> 6;
    const int wm   = wv % WVM;
    const int wn   = wv / WVM;
    const int lrow = lane & 15;
    const int lk8  = lane >> 4;
    const int row0 = blockIdx.x * BM;

    f32x4 acc[RT2][CT];
    #pragma unroll
    for (int rt = 0; rt < RT2; ++rt)
        #pragma unroll
        for (int ct = 0; ct < CT; ++ct) acc[rt][ct] = (f32x4){0.f, 0.f, 0.f, 0.f};

    for (int kb = 0; kb < NKB; ++kb) {
        if (kb) __syncthreads();
        const bool useA1 = (K2 == 0) || (kb * 64 < K1);
        {   // stage A tile
            const u16* Asel   = useA1 ? A1 : A2;
            const int astride = useA1 ? K1 : K2;
            const int aoff    = useA1 ? kb * 64 : kb * 64 - K1;
            for (int u = tid; u < BM * 8; u += 256) {
                const int r  = u >> 3, k8 = u & 7;
                const int row = row0 + r;
                uint4 v = make_uint4(0u, 0u, 0u, 0u);
                if (row < n)
                    v = *reinterpret_cast<const uint4*>(Asel + (size_t)row * astride + aoff + k8 * 8);
                sA[(r * 8 + k8) ^ (r & 7)] = v;
            }
        }
        {   // stage W^T
            u16* sWu = (u16*)sW;
            for (int u = tid; u < 64 * (C / 8); u += 256) {
                const int kk = u & 63, c8 = (u >> 6) * 8;
                const uint4 v = *reinterpret_cast<const uint4*>(W + (size_t)(kb * 64 + kk) * C + c8);
                const u16* e = (const u16*)&v;
                #pragma unroll
                for (int j = 0; j < 8; ++j) {
                    const int c = c8 + j;
                    sWu[(c * 64 + kk) ^ ((c & 7) << 3)] = e[j];
                }
            }
        }
        __syncthreads();
        #pragma unroll
        for (int ks = 0; ks < 2; ++ks) {
            short8 af[RT2];
            #pragma unroll
            for (int rt = 0; rt < RT2; ++rt) {
                const int r = (wm * RT2 + rt) * 16 + lrow;
                af[rt] = *reinterpret_cast<const short8*>(&sA[(r * 8 + ks * 4 + lk8) ^ (lrow & 7)]);
            }
            #pragma unroll
            for (int ct = 0; ct < CT; ++ct) {
                const int c = (wn * CT + ct) * 16 + lrow;
                const short8 bfr = *reinterpret_cast<const short8*>(&sW[(c * 8 + ks * 4 + lk8) ^ (lrow & 7)]);
                #pragma unroll
                for (int rt = 0; rt < RT2; ++rt)
                    acc[rt][ct] = __builtin_amdgcn_mfma_f32_16x16x32_bf16(af[rt], bfr, acc[rt][ct], 0, 0, 0);
            }
        }
    }

    // ---- epilogue (C/D layout: col=lane&15, row=(lane>>4)*4+reg) ----
    float vals[RT2][CT][4];
    #pragma unroll
    for (int ct = 0; ct < CT; ++ct) {
        const int colg = (wn * CT + ct) * 16 + lrow;
        const float bs = BIAS ? bias[colg] : 0.f;
        #pragma unroll
        for (int rt = 0; rt < RT2; ++rt)
            #pragma unroll
            for (int r = 0; r < 4; ++r) {
                float v = acc[rt][ct][r] + bs;
                if (EPI == 2 || EPI == 5) v = fmaxf(v, 0.f);
                vals[rt][ct][r] = v;
            }
    }

    if (EPI <= 2) {
        #pragma unroll
        for (int ct = 0; ct < CT; ++ct) {
            const int colg = (wn * CT + ct) * 16 + lrow;
            #pragma unroll
            for (int rt = 0; rt < RT2; ++rt) {
                const int rbase = row0 + (wm * RT2 + rt) * 16 + lk8 * 4;
                #pragma unroll
                for (int r = 0; r < 4; ++r) {
                    const int row = rbase + r;
                    if (row >= n) continue;
                    if (EPI == 0) Yf[(size_t)row * C + colg] = vals[rt][ct][r];
                    else          Yh[(size_t)row * C + colg] = f2b(vals[rt][ct][r]);
                }
            }
        }
    } else {
        // per-row cross-wave reduction (sum / sum-of-squares over C cols)
        #pragma unroll
        for (int rt = 0; rt < RT2; ++rt)
            #pragma unroll
            for (int r = 0; r < 4; ++r) {
                float pS = 0.f, pQ = 0.f;
                #pragma unroll
                for (int ct = 0; ct < CT; ++ct) { const float v = vals[rt][ct][r]; pS += v; pQ += v * v; }
                #pragma unroll
                for (int m = 1; m <= 8; m <<= 1) {
                    pS += __shfl_xor(pS, m, 64);
                    pQ += __shfl_xor(pQ, m, 64);
                }
                if (lrow == 0) {
                    const int rowl = (wm * RT2 + rt) * 16 + lk8 * 4 + r;
                    redS[wn][rowl] = pS; redQ[wn][rowl] = pQ;
                }
            }
        __syncthreads();
        #pragma unroll
        for (int rt = 0; rt < RT2; ++rt)
            #pragma unroll
            for (int r = 0; r < 4; ++r) {
                const int rowl = (wm * RT2 + rt) * 16 + lk8 * 4 + r;
                const int row = row0 + rowl;
                if (row >= n) continue;
                if (EPI == 3 || EPI == 4) {
                    const float ss  = redQ[0][rowl] + redQ[1][rowl];
                    const float inv = scale / fmaxf(sqrtf(ss), 1e-12f);
                    #pragma unroll
                    for (int ct = 0; ct < CT; ++ct) {
                        const int colg = (wn * CT + ct) * 16 + lrow;
                        float o = vals[rt][ct][r] * inv;
                        if (EPI == 4) o += Yf[(size_t)row * C + colg];
                        Yf[(size_t)row * C + colg] = o;
                    }
                } else { // EPI 5: relu already applied; LayerNorm
                    const float S = redS[0][rowl] + redS[1][rowl];
                    const float Q = redQ[0][rowl] + redQ[1][rowl];
                    const float mean = S * (1.0f / C);
                    const float var  = Q * (1.0f / C) - mean * mean;
                    const float inv  = 1.0f / sqrtf(var + 1e-5f);
                    #pragma unroll
                    for (int ct = 0; ct < CT; ++ct) {
                        const int colg = (wn * CT + ct) * 16 + lrow;
                        const float o = (vals[rt][ct][r] - mean) * inv * g[colg] + bvec[colg];
                        Yh[(size_t)row * C + colg] = f2b(o);
                    }
                }
            }
    }
}

// ---------------- CSR build (batched over 5 relations) ----------------
struct Rels { const int* e[5]; int E[5]; int rowoff[5]; };

__global__ __launch_bounds__(256)
void hist_all_k(Rels R, int* __restrict__ deg)
{
    const int ri = blockIdx.y;
    const int e = blockIdx.x * 256 + threadIdx.x;
    if (e < R.E[ri]) atomicAdd(&deg[R.rowoff[ri] + R.e[ri][e + R.E[ri]]], 1);
}

__global__ __launch_bounds__(256)
void fill_all_k(Rels R, const int* __restrict__ rowptr, int* __restrict__ next,
                int* __restrict__ colsrc)
{
    const int ri = blockIdx.y;
    const int e = blockIdx.x * 256 + threadIdx.x;
    if (e >= R.E[ri]) return;
    const int s = R.e[ri][e], d = R.e[ri][e + R.E[ri]];
    const int p = atomicAdd(&next[R.rowoff[ri] + d], 1);
    colsrc[rowptr[R.rowoff[ri] + d] + p] = s;
}

__global__ __launch_bounds__(256)
void scan1_k(const int* __restrict__ in, int* __restrict__ out, int* __restrict__ bsum, int n)
{
    __shared__ int wsum[4];
    const int base = blockIdx.x * 2048 + threadIdx.x * 8;
    int v[8]; int t = 0;
    #pragma unroll
    for (int k = 0; k < 8; ++k) { const int idx = base + k; v[k] = (idx < n) ? in[idx] : 0; t += v[k]; }
    int sc = t;
    #pragma unroll
    for (int off = 1; off < 64; off <<= 1) {
        const int u = __shfl_up(sc, off, 64);
        if ((threadIdx.x & 63) >= off) sc += u;
    }
    const int w = threadIdx.x >> 6, lane = threadIdx.x & 63;
    if (lane == 63) wsum[w] = sc;
    __syncthreads();
    int woff = 0;
    for (int i = 0; i < w; ++i) woff += wsum[i];
    int run = sc - t + woff;
    #pragma unroll
    for (int k = 0; k < 8; ++k) {
        const int idx = base + k;
        run += v[k];
        if (idx < n) out[idx + 1] = run;
    }
    if (threadIdx.x == 255) bsum[blockIdx.x] = run;
}

__global__ __launch_bounds__(256)
void scan2p_k(int* __restrict__ bsum, int nb)   // nb <= 256, single block
{
    __shared__ int ws[4];
    const int tid = threadIdx.x;
    const int v = (tid < nb) ? bsum[tid] : 0;
    int sc = v;
    #pragma unroll
    for (int off = 1; off < 64; off <<= 1) {
        const int u = __shfl_up(sc, off, 64);
        if ((tid & 63) >= off) sc += u;
    }
    if ((tid & 63) == 63) ws[tid >> 6] = sc;
    __syncthreads();
    int add = 0;
    for (int i = 0; i < (tid >> 6); ++i) add += ws[i];
    if (tid < nb) bsum[tid] = sc + add;
}

__global__ __launch_bounds__(256)
void scan3_k(int* __restrict__ rowptr, const int* __restrict__ bsum, int n)
{
    const int i = blockIdx.x * 256 + threadIdx.x;
    if (i == 0) rowptr[0] = 0;
    if (i < n) {
        const int b = i >> 11;
        if (b > 0) rowptr[i + 1] += bsum[b - 1];
    }
}

// ---------------- CSR mean-aggregate: 2 edges/wave, uint2 loads, strided bf16 out ----------------
// X: [*][128] bf16. out row stride rs (u16 elems), col offset co.
__global__ __launch_bounds__(256)
void agg128_k(const u16* __restrict__ X, const int* __restrict__ rowptr,
              const int* __restrict__ colsrc, int rowoff, int n, float scale,
              u16* __restrict__ out, int rs, int co)
{
    const int wid  = (int)((blockIdx.x * 256 + threadIdx.x) >> 6);
    const int lane = threadIdx.x & 63;
    if (wid >= n) return;
    const int beg = rowptr[rowoff + wid], end = rowptr[rowoff + wid + 1];
    const int sub = lane >> 5, cl = lane & 31;
    const uint2* X2 = (const uint2*)X;            // 4 ch per uint2, 32 per row
    float a0 = 0.f, a1 = 0.f, a2 = 0.f, a3 = 0.f;
    int j = beg + sub;
    for (; j + 2 < end; j += 4) {                 // j and j+2 both valid
        const int s0 = colsrc[j], s1 = colsrc[j + 2];
        const uint2 v0 = X2[(size_t)s0 * 32 + cl];
        const uint2 v1 = X2[(size_t)s1 * 32 + cl];
        a0 += blo(v0.x) + blo(v1.x); a1 += bhi(v0.x) + bhi(v1.x);
        a2 += blo(v0.y) + blo(v1.y); a3 += bhi(v0.y) + bhi(v1.y);
    }
    for (; j < end; j += 2) {
        const uint2 v = X2[(size_t)colsrc[j] * 32 + cl];
        a0 += blo(v.x); a1 += bhi(v.x); a2 += blo(v.y); a3 += bhi(v.y);
    }
    a0 += __shfl_xor(a0, 32, 64); a1 += __shfl_xor(a1, 32, 64);
    a2 += __shfl_xor(a2, 32, 64); a3 += __shfl_xor(a3, 32, 64);
    if (sub == 0) {
        const float m = scale / fmaxf((float)(end - beg), 1.0f);
        uint2 p;
        p.x = (u32)f2b(a0 * m) | ((u32)f2b(a1 * m) << 16);
        p.y = (u32)f2b(a2 * m) | ((u32)f2b(a3 * m) << 16);
        ((uint2*)(out + (size_t)wid * rs + co))[cl] = p;
    }
}

// X: [*][64] bf16. out dense [n][64].
__global__ __launch_bounds__(256)
void agg64_k(const u16* __restrict__ X, const int* __restrict__ rowptr,
             const int* __restrict__ colsrc, int rowoff, int n, float scale,
             u16* __restrict__ out)
{
    const int wid  = (int)((blockIdx.x * 256 + threadIdx.x) >> 6);
    const int lane = threadIdx.x & 63;
    if (wid >= n) return;
    const int beg = rowptr[rowoff + wid], end = rowptr[rowoff + wid + 1];
    const int sub = lane >> 5, cl = lane & 31;
    const u32* X1 = (const u32*)X;                // 2 ch per u32, 32 per row
    float a0 = 0.f, a1 = 0.f;
    int j = beg + sub;
    for (; j + 2 < end; j += 4) {
        const u32 v0 = X1[(size_t)colsrc[j] * 32 + cl];
        const u32 v1 = X1[(size_t)colsrc[j + 2] * 32 + cl];
        a0 += blo(v0) + blo(v1); a1 += bhi(v0) + bhi(v1);
    }
    for (; j < end; j += 2) {
        const u32 v = X1[(size_t)colsrc[j] * 32 + cl];
        a0 += blo(v); a1 += bhi(v);
    }
    a0 += __shfl_xor(a0, 32, 64); a1 += __shfl_xor(a1, 32, 64);
    if (sub == 0) {
        const float m = scale / fmaxf((float)(end - beg), 1.0f);
        ((u32*)(out + (size_t)wid * 64))[cl] = (u32)f2b(a0 * m) | ((u32)f2b(a1 * m) << 16);
    }
}

// ---------------- OUT(bf16) = LayerNorm(relu(X)) * g + b, X f32 n x 128 ----------------
__global__ __launch_bounds__(256)
void relu_ln16_k(const float* __restrict__ X, const float* __restrict__ g,
                 const float* __restrict__ b, u16* __restrict__ OUT, int n)
{
    const int wid  = (int)((blockIdx.x * 256 + threadIdx.x) >> 6);
    const int lane = threadIdx.x & 63;
    if (wid >= n) return;
    const float* x = X + (size_t)wid * 128;
    const float v0 = fmaxf(x[lane], 0.f), v1 = fmaxf(x[lane + 64], 0.f);
    float s = v0 + v1;
    #pragma unroll
    for (int off = 32; off > 0; off >>= 1) s += __shfl_xor(s, off, 64);
    const float m  = s * (1.0f / 128.0f);
    const float d0 = v0 - m, d1 = v1 - m;
    float vv = d0 * d0 + d1 * d1;
    #pragma unroll
    for (int off = 32; off > 0; off >>= 1) vv += __shfl_xor(vv, off, 64);
    const float inv = 1.0f / sqrtf(vv * (1.0f / 128.0f) + 1e-5f);
    OUT[(size_t)wid * 128 + lane]      = f2b(d0 * inv * g[lane]      + b[lane]);
    OUT[(size_t)wid * 128 + lane + 64] = f2b(d1 * inv * g[lane + 64] + b[lane + 64]);
}

// ---------------- weight prep ----------------
// concat [l0_Wl[r]; l0_Wr[r]] -> bf16 [r][128][128]
__global__ void l0wcat_k(const float* __restrict__ Wl, const float* __restrict__ Wr,
                         u16* __restrict__ out)
{
    const int r = blockIdx.y;
    const int idx = blockIdx.x * 256 + threadIdx.x;   // 0..16383
    const int row = idx >> 7, c = idx & 127;
    const float v = (row < 64) ? Wl[(size_t)r * 8192 + row * 128 + c]
                               : Wr[(size_t)r * 8192 + (row - 64) * 128 + c];
    out[(size_t)r * 16384 + idx] = f2b(v);
}

// note cat [li][512][128] = [Wl0;Wl1;Wl3;mean(Wr013)], beat cat [384][128] = [Wl2;Wl4;mean(Wr24)]
__global__ void wcat_k(const float* __restrict__ Wl, const float* __restrict__ Wr,
                       const float* __restrict__ bl, u16* __restrict__ WcatN,
                       u16* __restrict__ WcatB, float* __restrict__ bcatN,
                       float* __restrict__ bcatB)
{
    const int job = blockIdx.y;                       // 0,1: note li; 2: beat li=0
    const int idx = blockIdx.x * 256 + threadIdx.x;
    if (job < 2) {
        const int li = job;
        const float* WlL = Wl + (size_t)li * 5 * 16384;
        const float* WrL = Wr + (size_t)li * 5 * 16384;
        if (idx < 512 * 128) {
            const int row = idx >> 7, c = idx & 127;
            float v;
            if (row < 384) {
                const int rsel = row >> 7;
                const int rel = (rsel == 2) ? 3 : rsel;
                v = WlL[(size_t)rel * 16384 + (row & 127) * 128 + c];
            } else {
                const int rr = row - 384;
                v = (WrL[(size_t)0 * 16384 + rr * 128 + c] + WrL[(size_t)1 * 16384 + rr * 128 + c]
                   + WrL[(size_t)3 * 16384 + rr * 128 + c]) * (1.0f / 3.0f);
            }
            WcatN[(size_t)li * 512 * 128 + idx] = f2b(v);
        }
        if (blockIdx.x == 0 && threadIdx.x < 128) {
            const float* blL = bl + (size_t)li * 5 * 128;
            bcatN[li * 128 + threadIdx.x] =
                (blL[threadIdx.x] + blL[128 + threadIdx.x] + blL[3 * 128 + threadIdx.x]) * (1.0f / 3.0f);
        }
    } else {
        if (idx < 384 * 128) {
            const int row = idx >> 7, c = idx & 127;
            float v;
            if (row < 256) {
                const int rel = (row < 128) ? 2 : 4;
                v = Wl[(size_t)rel * 16384 + (row & 127) * 128 + c];
            } else {
                const int rr = row - 256;
                v = (Wr[(size_t)2 * 16384 + rr * 128 + c] + Wr[(size_t)4 * 16384 + rr * 128 + c]) * 0.5f;
            }
            WcatB[idx] = f2b(v);
        }
        if (blockIdx.x == 0 && threadIdx.x < 128)
            bcatB[threadIdx.x] = (bl[2 * 128 + threadIdx.x] + bl[4 * 128 + threadIdx.x]) * 0.5f;
    }
}

// fold eval BatchNorm into W2/b2 -> bf16 W2p, f32 b2p
__global__ void headprep_k(const float* __restrict__ W2, const float* __restrict__ b2,
                           const float* __restrict__ bng, const float* __restrict__ bnb,
                           u16* __restrict__ W2p16, float* __restrict__ b2p)
{
    const int idx = blockIdx.x * 256 + threadIdx.x;
    const float is = 1.0f / sqrtf(1.0f + 1e-5f);
    if (idx < 128 * 32) {
        const int k = idx >> 5;
        W2p16[idx] = f2b(W2[idx] * (bng[k] * is));
    }
    if (idx < 32) {
        float s = b2[idx];
        for (int k = 0; k < 128; ++k) s += bnb[k] * W2[k * 32 + idx];
        b2p[idx] = s;
    }
}

// batched f32 -> bf16 casts
struct CastJobs { const float* s[4]; u16* d[4]; int n[4]; };
__global__ __launch_bounds__(256)
void castmany_k(CastJobs J)
{
    const int j = blockIdx.y;
    const float* s = J.s[j]; u16* d = J.d[j]; const int n = J.n[j];
    for (int i = blockIdx.x * 256 + threadIdx.x; i < n; i += gridDim.x * 256)
        d[i] = f2b(s[i]);
}

// ---------------- orchestration ----------------
extern "C" void kernel_launch(void* const* d_in, const int* in_sizes, int n_in,
                              void* d_out, int out_size, void* d_ws, size_t ws_size,
                              hipStream_t stream)
{
    (void)n_in; (void)out_size; (void)ws_size;

    const float* x_note = (const float*)d_in[0];
    const float* x_beat = (const float*)d_in[1];
    const int*   e_on   = (const int*)d_in[2];
    const int*   e_co   = (const int*)d_in[3];
    const int*   e_nb   = (const int*)d_in[4];
    const int*   e_bn   = (const int*)d_in[5];
    const int*   e_bb   = (const int*)d_in[6];
    const float* proj_W = (const float*)d_in[7];
    const float* proj_b = (const float*)d_in[8];
    const float* l0_Wl  = (const float*)d_in[9];
    const float* l0_bl  = (const float*)d_in[10];
    const float* l0_Wr  = (const float*)d_in[11];
    const float* Wl     = (const float*)d_in[12];
    const float* bl     = (const float*)d_in[13];
    const float* Wr     = (const float*)d_in[14];
    const float* ln_g   = (const float*)d_in[15];
    const float* ln_b   = (const float*)d_in[16];
    const float* W1     = (const float*)d_in[17];
    const float* b1     = (const float*)d_in[18];
    const float* bn_g   = (const float*)d_in[19];
    const float* bn_b   = (const float*)d_in[20];
    const float* W2     = (const float*)d_in[21];
    const float* b2     = (const float*)d_in[22];

    const int E_on = in_sizes[2] / 2, E_co = in_sizes[3] / 2, E_nb = in_sizes[4] / 2,
              E_bn = in_sizes[5] / 2, E_bb = in_sizes[6] / 2;
    const int ETOT = E_on + E_co + E_nb + E_bn + E_bb;

    // ---- workspace layout ----
    char* wsb = (char*)d_ws;
    size_t off = 0;
    auto alloc = [&](size_t bytes) { char* p = wsb + off; off += (bytes + 255) & ~(size_t)255; return p; };
    float* nF    = (float*)alloc((size_t)NN * 128 * 4);   // layer-0 note accum (f32)
    float* bF    = (float*)alloc((size_t)NB * 128 * 4);   // layer-0 beat accum
    u16*  n16    = (u16*)alloc((size_t)NN * 128 * 2);     // note features bf16
    u16*  b16    = (u16*)alloc((size_t)NB * 128 * 2);     // beat features bf16
    u16*  agg16  = (u16*)alloc((size_t)NN * 384 * 2);     // concat aggregates (note), l0 agg, head tmp
    u16*  aggB   = (u16*)alloc((size_t)NB * 256 * 2);     // concat aggregates (beat)
    u16*  xn16   = n16;                                    // alias: x_note bf16 (layer 0)
    u16*  xb16   = b16;                                    // alias: x_beat bf16 (layer 0)
    u16*  n16h   = (u16*)nF;                               // alias: layer-2 out (nF dead then)
    u16*  proj16 = agg16 + (size_t)NN * 64;                // alias: proj out (clear of l0 agg region)
    u16*  tmp16h = agg16;                                  // alias: head hidden
    u16*  projW16 = (u16*)alloc(5 * 64 * 64 * 2);
    u16*  l0Wc16  = (u16*)alloc(5 * 128 * 128 * 2);
    u16*  WcatN   = (u16*)alloc(2 * 512 * 128 * 2);
    u16*  WcatB   = (u16*)alloc(384 * 128 * 2);
    u16*  W116    = (u16*)alloc(128 * 128 * 2);
    u16*  W2p16   = (u16*)alloc(128 * 32 * 2);
    float* bcatN  = (float*)alloc(2 * 128 * 4);
    float* bcatB  = (float*)alloc(128 * 4);
    float* b2p    = (float*)alloc(32 * 4);
    int* rowptr = (int*)alloc((LTOT + 64) * 4);
    int* deg    = (int*)alloc(LTOT * 4);
    int* colsrc = (int*)alloc((size_t)ETOT * 4);
    int* bsum   = (int*)alloc(256 * 4);

    Rels R;
    R.e[0] = e_on; R.e[1] = e_co; R.e[2] = e_nb; R.e[3] = e_bn; R.e[4] = e_bb;
    R.E[0] = E_on; R.E[1] = E_co; R.E[2] = E_nb; R.E[3] = E_bn; R.E[4] = E_bb;
    R.rowoff[0] = 0; R.rowoff[1] = NN; R.rowoff[2] = 2 * NN;
    R.rowoff[3] = 2 * NN + NB; R.rowoff[4] = 3 * NN + NB;
    int maxE = E_on;
    for (int i = 1; i < 5; ++i) if (R.E[i] > maxE) maxE = R.E[i];

    // ---- build concatenated CSR ----
    hipMemsetAsync(deg, 0, (size_t)LTOT * 4, stream);
    hist_all_k<<<dim3((maxE + 255) / 256, 5), 256, 0, stream>>>(R, deg);
    const int NBLK = (LTOT + 2047) / 2048;
    scan1_k<<<NBLK, 256, 0, stream>>>(deg, rowptr, bsum, LTOT);
    scan2p_k<<<1, 256, 0, stream>>>(bsum, NBLK);
    scan3_k<<<(LTOT + 255) / 256, 256, 0, stream>>>(rowptr, bsum, LTOT);
    hipMemsetAsync(deg, 0, (size_t)LTOT * 4, stream);
    fill_all_k<<<dim3((maxE + 255) / 256, 5), 256, 0, stream>>>(R, rowptr, deg, colsrc);

    // ---- weight prep + input casts ----
    l0wcat_k<<<dim3(64, 5), 256, 0, stream>>>(l0_Wl, l0_Wr, l0Wc16);
    wcat_k<<<dim3(256, 3), 256, 0, stream>>>(Wl, Wr, bl, WcatN, WcatB, bcatN, bcatB);
    headprep_k<<<16, 256, 0, stream>>>(W2, b2, bn_g, bn_b, W2p16, b2p);
    {
        CastJobs J;
        J.s[0] = x_note; J.d[0] = xn16;    J.n[0] = NN * 64;
        J.s[1] = x_beat; J.d[1] = xb16;    J.n[1] = NB * 64;
        J.s[2] = proj_W; J.d[2] = projW16; J.n[2] = 5 * 64 * 64;
        J.s[3] = W1;     J.d[3] = W116;    J.n[3] = 128 * 128;
        castmany_k<<<dim3(512, 4), 256, 0, stream>>>(J);
    }

    const int nsz[2] = {NN, NB};
    const int  relS[5] = {0, 0, 0, 1, 1};   // source type
    const int  relD[5] = {0, 0, 1, 0, 1};   // dst type
    const float Rdiv[2] = {3.0f, 2.0f};

    // ================= layer 0 (64 -> 128, per-rel l2norm fused into GEMM) ========
    for (int ri = 0; ri < 5; ++ri) {
        const u16* xs = relS[ri] == 0 ? xn16 : xb16;
        const u16* xd = relD[ri] == 0 ? xn16 : xb16;
        const int ns = nsz[relS[ri]], nd = nsz[relD[ri]];
        float* accum = relD[ri] == 0 ? nF : bF;
        const float sc = 1.0f / Rdiv[relD[ri]];
        // proj16 = relu(xs @ proj_W[ri] + proj_b[ri])
        gemm16_k<64, 0, 64, 2, true><<<(ns + 63) / 64, 256, 0, stream>>>(
            xs, nullptr, projW16 + (size_t)ri * 4096, proj_b + ri * 64,
            nullptr, nullptr, 0.f, nullptr, proj16, ns);
        // agg16[0:nd*64] = mean_{src} proj16
        agg64_k<<<(nd + 3) / 4, 256, 0, stream>>>(proj16, rowptr, colsrc, R.rowoff[ri], nd, 1.0f, agg16);
        // accum (=|+=) l2norm([agg|xd] @ l0Wcat[ri] + bl) / R_d   (fused epilogue)
        if (ri == 0 || ri == 2)
            gemm16_k<64, 64, 128, 3, true><<<(nd + 63) / 64, 256, 0, stream>>>(
                agg16, xd, l0Wc16 + (size_t)ri * 16384, l0_bl + ri * 128,
                nullptr, nullptr, sc, accum, nullptr, nd);
        else
            gemm16_k<64, 64, 128, 4, true><<<(nd + 63) / 64, 256, 0, stream>>>(
                agg16, xd, l0Wc16 + (size_t)ri * 16384, l0_bl + ri * 128,
                nullptr, nullptr, sc, accum, nullptr, nd);
    }
    relu_ln16_k<<<(NN + 3) / 4, 256, 0, stream>>>(nF, ln_g, ln_b, n16, NN);
    relu_ln16_k<<<(NB + 3) / 4, 256, 0, stream>>>(bF, ln_g, ln_b, b16, NB);

    // ================= layer 1 (K-concat; relu+LN fused) =================
    // note aggs -> agg16 [NN][384]; beat aggs -> aggB [NB][256]  (all read pre-update n16/b16)
    agg128_k<<<(NN + 3) / 4, 256, 0, stream>>>(n16, rowptr, colsrc, 0,            NN, 1.0f / 3.0f, agg16, 384, 0);
    agg128_k<<<(NN + 3) / 4, 256, 0, stream>>>(n16, rowptr, colsrc, NN,           NN, 1.0f / 3.0f, agg16, 384, 128);
    agg128_k<<<(NN + 3) / 4, 256, 0, stream>>>(b16, rowptr, colsrc, 2 * NN + NB,  NN, 1.0f / 3.0f, agg16, 384, 256);
    agg128_k<<<(NB + 3) / 4, 256, 0, stream>>>(n16, rowptr, colsrc, 2 * NN,       NB, 0.5f,        aggB, 256, 0);
    agg128_k<<<(NB + 3) / 4, 256, 0, stream>>>(b16, rowptr, colsrc, 3 * NN + NB,  NB, 0.5f,        aggB, 256, 128);
    // n16 = LN(relu([aggs|self] @ WcatN0 + bcatN0))   (in-place per-row-tile safe)
    gemm16_k<384, 128, 128, 5, true><<<(NN + 63) / 64, 256, 0, stream>>>(
        agg16, n16, WcatN, bcatN, ln_g + 128, ln_b + 128, 0.f, nullptr, n16, NN);
    gemm16_k<256, 128, 128, 5, true><<<(NB + 63) / 64, 256, 0, stream>>>(
        aggB, b16, WcatB, bcatB, ln_g + 128, ln_b + 128, 0.f, nullptr, b16, NB);

    // ================= layer 2 (notes only; beats unused downstream) ================
    agg128_k<<<(NN + 3) / 4, 256, 0, stream>>>(n16, rowptr, colsrc, 0,            NN, 1.0f / 3.0f, agg16, 384, 0);
    agg128_k<<<(NN + 3) / 4, 256, 0, stream>>>(n16, rowptr, colsrc, NN,           NN, 1.0f / 3.0f, agg16, 384, 128);
    agg128_k<<<(NN + 3) / 4, 256, 0, stream>>>(b16, rowptr, colsrc, 2 * NN + NB,  NN, 1.0f / 3.0f, agg16, 384, 256);
    gemm16_k<384, 128, 128, 1, true><<<(NN + 63) / 64, 256, 0, stream>>>(
        agg16, n16, WcatN + 512 * 128, bcatN + 128, nullptr, nullptr, 0.f, nullptr, n16h, NN);

    // ================= head =================
    gemm16_k<128, 0, 128, 2, true><<<(NN + 63) / 64, 256, 0, stream>>>(
        n16h, nullptr, W116, b1, nullptr, nullptr, 0.f, nullptr, tmp16h, NN);
    gemm16_k<128, 0, 32, 0, true><<<(NN + 127) / 128, 256, 0, stream>>>(
        tmp16h, nullptr, W2p16, b2p, nullptr, nullptr, 0.f, (float*)d_out, nullptr, NN);
}